// Round 1
// baseline (2312.979 us; speedup 1.0000x reference)
//
#include <hip/hip_runtime.h>
#include <math.h>

#define BB 128
#define NN 128
#define KK 16
#define MEDGE (BB*NN*KK)   // 262144 edges
#define MNODE (BB*NN)      // 16384 nodes

// ---------------------------------------------------------------- utilities

__device__ __forceinline__ unsigned ord32(float f) {
  unsigned u = __float_as_uint(f);
  return (u & 0x80000000u) ? ~u : (u | 0x80000000u);
}

__device__ __forceinline__ unsigned long long shfl_xor_u64(unsigned long long v, int m) {
  unsigned lo = (unsigned)(v & 0xffffffffull);
  unsigned hi = (unsigned)(v >> 32);
  lo = __shfl_xor(lo, m, 64);
  hi = __shfl_xor(hi, m, 64);
  return (((unsigned long long)hi) << 32) | (unsigned long long)lo;
}

// ---------------------------------------------------------------- kNN
// One wave (64 threads) per (b,n). Each lane owns nodes m=lane and m=lane+64.
// dist = sq[n] - 2*dot(n,m) + sq[m]  (reference formula; self-dist is exactly 0).
// Selection: 16 rounds of wave-min over packed (ordered_dist_bits, idx) — ties
// break to the lower index, matching jax.lax.top_k(-dist).
__global__ __launch_bounds__(64) void knn_kernel(const float* __restrict__ x, int C,
                                                 int* __restrict__ idx) {
  int bn = blockIdx.x;
  int b = bn >> 7, n = bn & 127;
  int lane = threadIdx.x;
  const float* xb = x + (size_t)b * NN * C;
  __shared__ float xn[128];
  for (int c = lane; c < C; c += 64) xn[c] = xb[n * C + c];
  __syncthreads();
  float sqn = 0.f;
  for (int c = 0; c < C; ++c) sqn = fmaf(xn[c], xn[c], sqn);

  unsigned long long key[2];
#pragma unroll
  for (int t = 0; t < 2; ++t) {
    int m = lane + 64 * t;
    const float* xm = xb + (size_t)m * C;
    float dot = 0.f, sqm = 0.f;
    for (int c = 0; c < C; ++c) {
      float v = xm[c];
      dot = fmaf(xn[c], v, dot);
      sqm = fmaf(v, v, sqm);
    }
    float d = sqn - 2.f * dot + sqm;
    key[t] = (((unsigned long long)ord32(d)) << 32) | (unsigned)m;
  }

  int* out = idx + (size_t)bn * KK;
  for (int r = 0; r < KK; ++r) {
    unsigned long long mk = key[0] < key[1] ? key[0] : key[1];
#pragma unroll
    for (int off = 32; off > 0; off >>= 1) {
      unsigned long long o = shfl_xor_u64(mk, off);
      if (o < mk) mk = o;
    }
    int wm = (int)(mk & 0xffffffffu);
    if (lane == 0) out[r] = wm;
    if ((wm & 63) == lane) key[wm >> 6] = ~0ull;  // remove winner
  }
}

// ---------------------------------------------------------------- node GEMM
// p = x @ (W1_top - W1_bot),  q = x @ W1_bot    (W1 is [2*Cin, Cout] row-major)
__global__ __launch_bounds__(256) void node_gemm(const float* __restrict__ x,
                                                 const float* __restrict__ W,
                                                 float* __restrict__ p, float* __restrict__ q,
                                                 int Cin, int Cout) {
  int c = threadIdx.x;
  __shared__ float xr[128];
  for (int r = 0; r < 8; ++r) {
    int row = blockIdx.x * 8 + r;
    __syncthreads();
    for (int i = c; i < Cin; i += blockDim.x) xr[i] = x[(size_t)row * Cin + i];
    __syncthreads();
    float a = 0.f, qv = 0.f;
    for (int i = 0; i < Cin; ++i) {
      float xv = xr[i];
      a  = fmaf(xv, W[i * Cout + c], a);
      qv = fmaf(xv, W[(Cin + i) * Cout + c], qv);
    }
    p[(size_t)row * Cout + c] = a - qv;
    q[(size_t)row * Cout + c] = qv;
  }
}

// ---------------------------------------------------------------- BN1 stats over edges
// y[b,n,k,c] = p[b,n,c] + q[b,idx,c] + b1[c]; accumulate sum / sumsq per channel.
__global__ __launch_bounds__(256) void edge_stats1(const float* __restrict__ p,
                                                   const float* __restrict__ q,
                                                   const float* __restrict__ b1,
                                                   const int* __restrict__ idx,
                                                   float* __restrict__ s1, float* __restrict__ ss1,
                                                   int C) {
  int c = threadIdx.x;
  float s = 0.f, ss = 0.f;
  float bias = b1[c];
  for (int ni = 0; ni < 16; ++ni) {
    int bn = blockIdx.x * 16 + ni;
    int b = bn >> 7;
    const int* id = idx + (size_t)bn * KK;
    float pv = p[(size_t)bn * C + c] + bias;
#pragma unroll
    for (int k = 0; k < KK; ++k) {
      int j = id[k];
      float y = pv + q[(size_t)(b * NN + j) * C + c];
      s += y;
      ss = fmaf(y, y, ss);
    }
  }
  atomicAdd(&s1[c], s);
  atomicAdd(&ss1[c], ss);
}

// ---------------------------------------------------------------- BN params
__global__ void bn_params(const float* __restrict__ s, const float* __restrict__ ss,
                          const float* __restrict__ g, const float* __restrict__ beta,
                          float M, float* __restrict__ scale, float* __restrict__ shift) {
  int c = threadIdx.x;
  float mean = s[c] / M;
  float var = ss[c] / M - mean * mean;
  if (var < 0.f) var = 0.f;
  float sc = g[c] * rsqrtf(var + 1e-5f);
  scale[c] = sc;
  shift[c] = beta[c] - mean * sc;
}

// ---------------------------------------------------------------- edge GEMM2
// Per node: build h1[k][c] = ReLU(BN1(y)) in LDS, z = h1 @ W2 + b2,
// accumulate BN2 sum/sumsq per channel + per-node max/min over k.
__global__ __launch_bounds__(256) void edge_gemm2(const float* __restrict__ p,
                                                  const float* __restrict__ q,
                                                  const float* __restrict__ b1,
                                                  const int* __restrict__ idx,
                                                  const float* __restrict__ sc1,
                                                  const float* __restrict__ sh1,
                                                  const float* __restrict__ W2,
                                                  const float* __restrict__ b2,
                                                  float* __restrict__ zmax, float* __restrict__ zmin,
                                                  float* __restrict__ s2, float* __restrict__ ss2,
                                                  int C) {
  int c = threadIdx.x;
  __shared__ __align__(16) float h1s[KK * 256];
  float s = 0.f, ss = 0.f;
  float scl = sc1[c], shf = sh1[c], bias1 = b1[c], bias2 = b2[c];
  for (int ni = 0; ni < 16; ++ni) {
    int bn = blockIdx.x * 16 + ni;
    int b = bn >> 7;
    const int* id = idx + (size_t)bn * KK;
    __syncthreads();
    float pv = p[(size_t)bn * C + c] + bias1;
#pragma unroll
    for (int k = 0; k < KK; ++k) {
      int j = id[k];
      float y = pv + q[(size_t)(b * NN + j) * C + c];
      h1s[k * C + c] = fmaxf(fmaf(y, scl, shf), 0.f);
    }
    __syncthreads();
    float acc[KK];
#pragma unroll
    for (int k = 0; k < KK; ++k) acc[k] = bias2;
    for (int kk = 0; kk < C; kk += 4) {
      float w0 = W2[(kk + 0) * C + c];
      float w1 = W2[(kk + 1) * C + c];
      float w2 = W2[(kk + 2) * C + c];
      float w3 = W2[(kk + 3) * C + c];
#pragma unroll
      for (int k = 0; k < KK; ++k) {
        const float4 h4 = *(const float4*)(&h1s[k * C + kk]);
        acc[k] = fmaf(h4.x, w0, acc[k]);
        acc[k] = fmaf(h4.y, w1, acc[k]);
        acc[k] = fmaf(h4.z, w2, acc[k]);
        acc[k] = fmaf(h4.w, w3, acc[k]);
      }
    }
    float mx = acc[0], mn = acc[0];
#pragma unroll
    for (int k = 0; k < KK; ++k) {
      float z = acc[k];
      s += z;
      ss = fmaf(z, z, ss);
      mx = fmaxf(mx, z);
      mn = fminf(mn, z);
    }
    zmax[(size_t)bn * C + c] = mx;
    zmin[(size_t)bn * C + c] = mn;
  }
  atomicAdd(&s2[c], s);
  atomicAdd(&ss2[c], ss);
}

// ---------------------------------------------------------------- finalize
// max_k ReLU(s*z+t) = ReLU(s*(s>=0 ? max_k z : min_k z) + t)
__global__ __launch_bounds__(256) void finalize_kernel(const float* __restrict__ zmax,
                                                       const float* __restrict__ zmin,
                                                       const float* __restrict__ sc2,
                                                       const float* __restrict__ sh2,
                                                       float* __restrict__ out, int Cmask) {
  int t = blockIdx.x * 256 + threadIdx.x;
  int c = t & Cmask;
  float scl = sc2[c];
  float v = (scl >= 0.f) ? zmax[t] : zmin[t];
  out[t] = fmaxf(fmaf(v, scl, sh2[c]), 0.f);
}

// ---------------------------------------------------------------- pooling
__global__ __launch_bounds__(256) void pool_kernel(const float* __restrict__ h,
                                                   float* __restrict__ pooled) {
  int b = blockIdx.x, c = threadIdx.x;
  float s = 0.f, mx = -INFINITY;
  for (int n = 0; n < NN; ++n) {
    float v = h[(size_t)(b * NN + n) * 256 + c];
    s += v;
    mx = fmaxf(mx, v);
  }
  pooled[b * 512 + c] = s * (1.f / 128.f);
  pooled[b * 512 + 256 + c] = mx;
}

// ---------------------------------------------------------------- FC layers
__global__ __launch_bounds__(256) void fc_gemm(const float* __restrict__ in,
                                               const float* __restrict__ W,
                                               const float* __restrict__ bias,
                                               float* __restrict__ outm, int Cin, int Cout) {
  int b = blockIdx.x, c = threadIdx.x;
  __shared__ float row[512];
  for (int i = c; i < Cin; i += blockDim.x) row[i] = in[b * Cin + i];
  __syncthreads();
  float acc = bias[c];
  for (int i = 0; i < Cin; ++i) acc = fmaf(row[i], W[i * Cout + c], acc);
  outm[b * Cout + c] = acc;
}

// Training-mode BN over rows (two-pass) + ReLU, in place. One block, C threads.
__global__ void bn_relu_rows(float* __restrict__ t, const float* __restrict__ g,
                             const float* __restrict__ beta, int rows, int C) {
  int c = threadIdx.x;
  float s = 0.f;
  for (int r = 0; r < rows; ++r) s += t[r * C + c];
  float mean = s / (float)rows;
  float v = 0.f;
  for (int r = 0; r < rows; ++r) {
    float d = t[r * C + c] - mean;
    v = fmaf(d, d, v);
  }
  v /= (float)rows;
  float scl = g[c] * rsqrtf(v + 1e-5f);
  float shf = beta[c] - mean * scl;
  for (int r = 0; r < rows; ++r)
    t[r * C + c] = fmaxf(fmaf(t[r * C + c], scl, shf), 0.f);
}

__global__ __launch_bounds__(256) void fc3_kernel(const float* __restrict__ t2,
                                                  const float* __restrict__ W,
                                                  const float* __restrict__ bias,
                                                  float* __restrict__ out) {
  int t = threadIdx.x;  // 256 = 128 rows * 2 cols
  int b = t >> 1, j = t & 1;
  float acc = bias[j];
  for (int r = 0; r < 128; ++r) acc = fmaf(t2[b * 128 + r], W[r * 2 + j], acc);
  out[t] = acc;
}

// ---------------------------------------------------------------- launch

extern "C" void kernel_launch(void* const* d_in, const int* in_sizes, int n_in,
                              void* d_out, int out_size, void* d_ws, size_t ws_size,
                              hipStream_t stream) {
  const float* x   = (const float*)d_in[0];
  const float* w11 = (const float*)d_in[1];
  const float* b11 = (const float*)d_in[2];
  const float* g11 = (const float*)d_in[3];
  const float* e11 = (const float*)d_in[4];
  const float* w12 = (const float*)d_in[5];
  const float* b12 = (const float*)d_in[6];
  const float* g12 = (const float*)d_in[7];
  const float* e12 = (const float*)d_in[8];
  const float* w21 = (const float*)d_in[9];
  const float* b21 = (const float*)d_in[10];
  const float* g21 = (const float*)d_in[11];
  const float* e21 = (const float*)d_in[12];
  const float* w22 = (const float*)d_in[13];
  const float* b22 = (const float*)d_in[14];
  const float* g22 = (const float*)d_in[15];
  const float* e22 = (const float*)d_in[16];
  const float* w31 = (const float*)d_in[17];
  const float* b31 = (const float*)d_in[18];
  const float* g31 = (const float*)d_in[19];
  const float* e31 = (const float*)d_in[20];
  const float* w32 = (const float*)d_in[21];
  const float* b32 = (const float*)d_in[22];
  const float* g32 = (const float*)d_in[23];
  const float* e32 = (const float*)d_in[24];
  const float* fw1 = (const float*)d_in[25];
  const float* fb1 = (const float*)d_in[26];
  const float* fg1 = (const float*)d_in[27];
  const float* fe1 = (const float*)d_in[28];
  const float* fw2 = (const float*)d_in[29];
  const float* fb2 = (const float*)d_in[30];
  const float* fg2 = (const float*)d_in[31];
  const float* fe2 = (const float*)d_in[32];
  const float* fw3 = (const float*)d_in[33];
  const float* fb3 = (const float*)d_in[34];

  char* wsb = (char*)d_ws;
  size_t o = 0;
  auto alloc = [&](size_t bytes) -> void* {
    void* r = wsb + o;
    o += (bytes + 255) & ~(size_t)255;
    return r;
  };
  int*   idx    = (int*)  alloc((size_t)MNODE * KK * sizeof(int));
  float* p      = (float*)alloc((size_t)MNODE * 256 * sizeof(float));
  float* q      = (float*)alloc((size_t)MNODE * 256 * sizeof(float));
  float* zmx    = (float*)alloc((size_t)MNODE * 256 * sizeof(float));
  float* zmn    = (float*)alloc((size_t)MNODE * 256 * sizeof(float));
  float* h1buf  = (float*)alloc((size_t)MNODE * 64  * sizeof(float));
  float* h2buf  = (float*)alloc((size_t)MNODE * 128 * sizeof(float));
  float* h3buf  = (float*)alloc((size_t)MNODE * 256 * sizeof(float));
  float* stats  = (float*)alloc(8 * 256 * sizeof(float));
  float* pooled = (float*)alloc(128 * 512 * sizeof(float));
  float* t1     = (float*)alloc(128 * 256 * sizeof(float));
  float* t2     = (float*)alloc(128 * 128 * sizeof(float));

  float* s1  = stats;
  float* ss1 = stats + 256;
  float* s2  = stats + 512;
  float* ss2 = stats + 768;
  float* sc1 = stats + 1024;
  float* sh1 = stats + 1280;
  float* sc2 = stats + 1536;
  float* sh2 = stats + 1792;

  auto edgeconv = [&](const float* xin, int Cin, int Cout,
                      const float* W1, const float* b1, const float* g1, const float* e1,
                      const float* W2, const float* b2, const float* g2, const float* e2,
                      float* hout) {
    hipMemsetAsync(stats, 0, 4 * 256 * sizeof(float), stream);
    knn_kernel<<<dim3(MNODE), dim3(64), 0, stream>>>(xin, Cin, idx);
    node_gemm<<<dim3(MNODE / 8), dim3(Cout), 0, stream>>>(xin, W1, p, q, Cin, Cout);
    edge_stats1<<<dim3(MNODE / 16), dim3(Cout), 0, stream>>>(p, q, b1, idx, s1, ss1, Cout);
    bn_params<<<dim3(1), dim3(Cout), 0, stream>>>(s1, ss1, g1, e1, (float)MEDGE, sc1, sh1);
    edge_gemm2<<<dim3(MNODE / 16), dim3(Cout), 0, stream>>>(p, q, b1, idx, sc1, sh1, W2, b2,
                                                            zmx, zmn, s2, ss2, Cout);
    bn_params<<<dim3(1), dim3(Cout), 0, stream>>>(s2, ss2, g2, e2, (float)MEDGE, sc2, sh2);
    finalize_kernel<<<dim3(MNODE * Cout / 256), dim3(256), 0, stream>>>(zmx, zmn, sc2, sh2,
                                                                        hout, Cout - 1);
  };

  edgeconv(x,     6,   64,  w11, b11, g11, e11, w12, b12, g12, e12, h1buf);
  edgeconv(h1buf, 64,  128, w21, b21, g21, e21, w22, b22, g22, e22, h2buf);
  edgeconv(h2buf, 128, 256, w31, b31, g31, e31, w32, b32, g32, e32, h3buf);

  pool_kernel<<<dim3(BB), dim3(256), 0, stream>>>(h3buf, pooled);
  fc_gemm<<<dim3(BB), dim3(256), 0, stream>>>(pooled, fw1, fb1, t1, 512, 256);
  bn_relu_rows<<<dim3(1), dim3(256), 0, stream>>>(t1, fg1, fe1, 128, 256);
  fc_gemm<<<dim3(BB), dim3(128), 0, stream>>>(t1, fw2, fb2, t2, 256, 128);
  bn_relu_rows<<<dim3(1), dim3(128), 0, stream>>>(t2, fg2, fe2, 128, 128);
  fc3_kernel<<<dim3(1), dim3(256), 0, stream>>>(t2, fw3, fb3, (float*)d_out);
}

// Round 3
// 1984.767 us; speedup vs baseline: 1.1654x; 1.1654x over previous
//
#include <hip/hip_runtime.h>
#include <math.h>

#define BB 128
#define NN 128
#define KK 16
#define MEDGE (BB*NN*KK)   // 262144 edges
#define MNODE (BB*NN)      // 16384 nodes

typedef __bf16 bf16x8 __attribute__((ext_vector_type(8)));
typedef float  floatx16 __attribute__((ext_vector_type(16)));
typedef unsigned short u16;
typedef u16 ushort8_alias __attribute__((ext_vector_type(8)));

// ---------------------------------------------------------------- utilities

__device__ __forceinline__ unsigned ord32(float f) {
  unsigned u = __float_as_uint(f);
  return (u & 0x80000000u) ? ~u : (u | 0x80000000u);
}

__device__ __forceinline__ unsigned long long shfl_xor_u64(unsigned long long v, int m) {
  unsigned lo = (unsigned)(v & 0xffffffffull);
  unsigned hi = (unsigned)(v >> 32);
  lo = __shfl_xor(lo, m, 64);
  hi = __shfl_xor(hi, m, 64);
  return (((unsigned long long)hi) << 32) | (unsigned long long)lo;
}

// ---------------------------------------------------------------- kNN
__global__ __launch_bounds__(64) void knn_kernel(const float* __restrict__ x, int C,
                                                 int* __restrict__ idx) {
  int bn = blockIdx.x;
  int b = bn >> 7, n = bn & 127;
  int lane = threadIdx.x;
  const float* xb = x + (size_t)b * NN * C;
  __shared__ float xn[256];
  for (int c = lane; c < C; c += 64) xn[c] = xb[n * C + c];
  __syncthreads();
  float sqn = 0.f;
  for (int c = 0; c < C; ++c) sqn = fmaf(xn[c], xn[c], sqn);

  unsigned long long key[2];
#pragma unroll
  for (int t = 0; t < 2; ++t) {
    int m = lane + 64 * t;
    const float* xm = xb + (size_t)m * C;
    float dot = 0.f, sqm = 0.f;
    for (int c = 0; c < C; ++c) {
      float v = xm[c];
      dot = fmaf(xn[c], v, dot);
      sqm = fmaf(v, v, sqm);
    }
    float d = sqn - 2.f * dot + sqm;
    key[t] = (((unsigned long long)ord32(d)) << 32) | (unsigned)m;
  }

  int* out = idx + (size_t)bn * KK;
  for (int r = 0; r < KK; ++r) {
    unsigned long long mk = key[0] < key[1] ? key[0] : key[1];
#pragma unroll
    for (int off = 32; off > 0; off >>= 1) {
      unsigned long long o = shfl_xor_u64(mk, off);
      if (o < mk) mk = o;
    }
    int wm = (int)(mk & 0xffffffffu);
    if (lane == 0) out[r] = wm;
    if ((wm & 63) == lane) key[wm >> 6] = ~0ull;
  }
}

// ---------------------------------------------------------------- node GEMM
// p = x @ (W1_top - W1_bot),  q = x @ W1_bot    (W1 is [2*Cin, Cout] row-major)
__global__ __launch_bounds__(256) void node_gemm(const float* __restrict__ x,
                                                 const float* __restrict__ W,
                                                 float* __restrict__ p, float* __restrict__ q,
                                                 int Cin, int Cout) {
  int c = threadIdx.x;
  __shared__ float xr[128];
  for (int r = 0; r < 8; ++r) {
    int row = blockIdx.x * 8 + r;
    __syncthreads();
    for (int i = c; i < Cin; i += blockDim.x) xr[i] = x[(size_t)row * Cin + i];
    __syncthreads();
    float a = 0.f, qv = 0.f;
    for (int i = 0; i < Cin; ++i) {
      float xv = xr[i];
      a  = fmaf(xv, W[i * Cout + c], a);
      qv = fmaf(xv, W[(Cin + i) * Cout + c], qv);
    }
    p[(size_t)row * Cout + c] = a - qv;
    q[(size_t)row * Cout + c] = qv;
  }
}

// ---------------------------------------------------------------- BN1 stats over edges
__global__ __launch_bounds__(256) void edge_stats1(const float* __restrict__ p,
                                                   const float* __restrict__ q,
                                                   const float* __restrict__ b1,
                                                   const int* __restrict__ idx,
                                                   float* __restrict__ s1, float* __restrict__ ss1,
                                                   int C) {
  int c = threadIdx.x;
  float s = 0.f, ss = 0.f;
  float bias = b1[c];
  for (int ni = 0; ni < 16; ++ni) {
    int bn = blockIdx.x * 16 + ni;
    int b = bn >> 7;
    const int* id = idx + (size_t)bn * KK;
    float pv = p[(size_t)bn * C + c] + bias;
#pragma unroll
    for (int k = 0; k < KK; ++k) {
      int j = id[k];
      float y = pv + q[(size_t)(b * NN + j) * C + c];
      s += y;
      ss = fmaf(y, y, ss);
    }
  }
  atomicAdd(&s1[c], s);
  atomicAdd(&ss1[c], ss);
}

// ---------------------------------------------------------------- BN params
// shift = beta - mean*scale (+ scale*bias folded in when bias != null)
__global__ void bn_params(const float* __restrict__ s, const float* __restrict__ ss,
                          const float* __restrict__ g, const float* __restrict__ beta,
                          const float* __restrict__ bias,
                          float M, float* __restrict__ scale, float* __restrict__ shift) {
  int c = threadIdx.x;
  float mean = s[c] / M;
  float var = ss[c] / M - mean * mean;
  if (var < 0.f) var = 0.f;
  float sc = g[c] * rsqrtf(var + 1e-5f);
  scale[c] = sc;
  float sh = beta[c] - mean * sc;
  if (bias) sh += sc * bias[c];
  shift[c] = sh;
}

// ---------------------------------------------------------------- W2 packing
// Fragment order for v_mfma_f32_32x32x16_bf16 B operand:
// B[k][n], n = lane&31, k = (lane>>5)*8 + j. Flat index ((kt*NT+nt)*64+lane)*8+j.
__device__ __forceinline__ u16 bf16_rne_bits(float x) {
  unsigned u = __float_as_uint(x);
  return (u16)((u + 0x7FFF + ((u >> 16) & 1)) >> 16);
}

template<int C>
__global__ __launch_bounds__(256) void pack_w2(const float* __restrict__ W,
                                               u16* __restrict__ Wh, u16* __restrict__ Wl) {
  int t = blockIdx.x * 256 + threadIdx.x;
  if (t >= C * C) return;
  constexpr int NT = C / 32;
  int j = t & 7, lane = (t >> 3) & 63, ktnt = t >> 9;
  int nt = ktnt % NT, kt = ktnt / NT;
  int row = kt * 16 + (lane >> 5) * 8 + j;
  int col = nt * 32 + (lane & 31);
  float w = W[row * C + col];
  u16 h = bf16_rne_bits(w);
  float hf = __uint_as_float(((unsigned)h) << 16);
  Wh[t] = h;
  Wl[t] = bf16_rne_bits(w - hf);
}

// ---------------------------------------------------------------- MFMA edge GEMM2
// Per wave: 2 M-tiles (= 4 nodes, M=32 each: 2 nodes x 16 neighbors), both
// A-halves (bf16 hi/lo split) register-resident, W2 frags streamed from packed
// global (L2). z = Ah*Bh + Al*Bh + Ah*Bl accumulated fp32 (incl. bias2).
// Epilogue: per-node max/min over k + BN2 sum/sumsq straight from acc regs.
template<int C>
__global__ __launch_bounds__(64, 1) void edge_gemm2_mfma(
    const float* __restrict__ p, const float* __restrict__ q,
    const int* __restrict__ idx,
    const float* __restrict__ sc1, const float* __restrict__ sh1,  // bias1 folded into sh1
    const u16* __restrict__ Wh, const u16* __restrict__ Wl,
    const float* __restrict__ b2,
    float* __restrict__ zmax, float* __restrict__ zmin,
    float* __restrict__ s2, float* __restrict__ ss2) {
  constexpr int KT = C / 16, NT = C / 32, NTP = C / 64, U = 2;
  int lane = threadIdx.x;
  int m = lane & 31, lh = lane >> 5;

  float sArr[NT], ssArr[NT];
#pragma unroll
  for (int i = 0; i < NT; ++i) { sArr[i] = 0.f; ssArr[i] = 0.f; }

  for (int u = 0; u < U; ++u) {
    int nodeBase = (blockIdx.x * U + u) * 4;

    // ---- build A fragments directly in registers (hi + lo bf16 split)
    bf16x8 Ah[2][KT], Al[2][KT];
#pragma unroll
    for (int mt = 0; mt < 2; ++mt) {
      int nd = nodeBase + mt * 2 + (m >> 4);
      int b = nd >> 7;
      int j = idx[nd * KK + (m & 15)];
      const float* pr = p + (size_t)nd * C;
      const float* qr = q + (size_t)(b * NN + j) * C;
#pragma unroll
      for (int kt = 0; kt < KT; ++kt) {
        int c0 = kt * 16 + lh * 8;
        float4 pa = *(const float4*)(pr + c0);
        float4 pb = *(const float4*)(pr + c0 + 4);
        float4 qa = *(const float4*)(qr + c0);
        float4 qb = *(const float4*)(qr + c0 + 4);
        float4 sa = *(const float4*)(sc1 + c0);
        float4 sb = *(const float4*)(sc1 + c0 + 4);
        float4 ta = *(const float4*)(sh1 + c0);
        float4 tb = *(const float4*)(sh1 + c0 + 4);
        float hv[8];
        hv[0] = fmaxf(fmaf(pa.x + qa.x, sa.x, ta.x), 0.f);
        hv[1] = fmaxf(fmaf(pa.y + qa.y, sa.y, ta.y), 0.f);
        hv[2] = fmaxf(fmaf(pa.z + qa.z, sa.z, ta.z), 0.f);
        hv[3] = fmaxf(fmaf(pa.w + qa.w, sa.w, ta.w), 0.f);
        hv[4] = fmaxf(fmaf(pb.x + qb.x, sb.x, tb.x), 0.f);
        hv[5] = fmaxf(fmaf(pb.y + qb.y, sb.y, tb.y), 0.f);
        hv[6] = fmaxf(fmaf(pb.z + qb.z, sb.z, tb.z), 0.f);
        hv[7] = fmaxf(fmaf(pb.w + qb.w, sb.w, tb.w), 0.f);
        bf16x8 ah, al;
#pragma unroll
        for (int t = 0; t < 8; ++t) {
          __bf16 hb = (__bf16)hv[t];
          float lo = hv[t] - (float)hb;
          ah[t] = hb;
          al[t] = (__bf16)lo;
        }
        Ah[mt][kt] = ah;
        Al[mt][kt] = al;
      }
    }

    // ---- GEMM over column-tile pairs
#pragma unroll
    for (int ntp = 0; ntp < NTP; ++ntp) {
      floatx16 acc[2][2];
#pragma unroll
      for (int mt = 0; mt < 2; ++mt)
#pragma unroll
        for (int n2 = 0; n2 < 2; ++n2) {
          float bv = b2[ntp * 64 + n2 * 32 + m];
#pragma unroll
          for (int r = 0; r < 16; ++r) acc[mt][n2][r] = bv;
        }

#pragma unroll
      for (int kt = 0; kt < KT; ++kt) {
        int e0 = (kt * NT + ntp * 2) * 64 + lane;  // ushort8 element index
        bf16x8 bh0 = __builtin_bit_cast(bf16x8, ((const ushort8_alias*)Wh)[e0]);
        bf16x8 bh1 = __builtin_bit_cast(bf16x8, ((const ushort8_alias*)Wh)[e0 + 64]);
        bf16x8 bl0 = __builtin_bit_cast(bf16x8, ((const ushort8_alias*)Wl)[e0]);
        bf16x8 bl1 = __builtin_bit_cast(bf16x8, ((const ushort8_alias*)Wl)[e0 + 64]);
#pragma unroll
        for (int mt = 0; mt < 2; ++mt) {
          acc[mt][0] = __builtin_amdgcn_mfma_f32_32x32x16_bf16(Ah[mt][kt], bh0, acc[mt][0], 0, 0, 0);
          acc[mt][0] = __builtin_amdgcn_mfma_f32_32x32x16_bf16(Al[mt][kt], bh0, acc[mt][0], 0, 0, 0);
          acc[mt][0] = __builtin_amdgcn_mfma_f32_32x32x16_bf16(Ah[mt][kt], bl0, acc[mt][0], 0, 0, 0);
          acc[mt][1] = __builtin_amdgcn_mfma_f32_32x32x16_bf16(Ah[mt][kt], bh1, acc[mt][1], 0, 0, 0);
          acc[mt][1] = __builtin_amdgcn_mfma_f32_32x32x16_bf16(Al[mt][kt], bh1, acc[mt][1], 0, 0, 0);
          acc[mt][1] = __builtin_amdgcn_mfma_f32_32x32x16_bf16(Ah[mt][kt], bl1, acc[mt][1], 0, 0, 0);
        }
      }

      // ---- epilogue: acc row = (r&3)+8*(r>>2)+4*lh, col = lane&31.
      // regs 0..7 -> rows 0..15 (node A's 16 neighbors), regs 8..15 -> node B.
#pragma unroll
      for (int mt = 0; mt < 2; ++mt)
#pragma unroll
        for (int n2 = 0; n2 < 2; ++n2) {
          float s = 0.f, ss = 0.f;
          float mxA = -INFINITY, mnA = INFINITY, mxB = -INFINITY, mnB = INFINITY;
#pragma unroll
          for (int r = 0; r < 8; ++r) {
            float z = acc[mt][n2][r];
            s += z; ss = fmaf(z, z, ss);
            mxA = fmaxf(mxA, z); mnA = fminf(mnA, z);
          }
#pragma unroll
          for (int r = 8; r < 16; ++r) {
            float z = acc[mt][n2][r];
            s += z; ss = fmaf(z, z, ss);
            mxB = fmaxf(mxB, z); mnB = fminf(mnB, z);
          }
          sArr[ntp * 2 + n2] += s;
          ssArr[ntp * 2 + n2] += ss;
          mxA = fmaxf(mxA, __shfl_xor(mxA, 32)); mnA = fminf(mnA, __shfl_xor(mnA, 32));
          mxB = fmaxf(mxB, __shfl_xor(mxB, 32)); mnB = fminf(mnB, __shfl_xor(mnB, 32));
          if (lane < 32) {
            int ndA = nodeBase + mt * 2;
            int col = ntp * 64 + n2 * 32 + m;
            zmax[(size_t)ndA * C + col] = mxA;
            zmin[(size_t)ndA * C + col] = mnA;
            zmax[(size_t)(ndA + 1) * C + col] = mxB;
            zmin[(size_t)(ndA + 1) * C + col] = mnB;
          }
        }
    }
  }

  // ---- BN2 stats: lane-half combine, then one atomic per channel per wave
#pragma unroll
  for (int nt = 0; nt < NT; ++nt) {
    float s = sArr[nt] + __shfl_xor(sArr[nt], 32);
    float ss = ssArr[nt] + __shfl_xor(ssArr[nt], 32);
    if (lane < 32) {
      atomicAdd(&s2[nt * 32 + m], s);
      atomicAdd(&ss2[nt * 32 + m], ss);
    }
  }
}

// ---------------------------------------------------------------- finalize
// max_k ReLU(s*z+t) = ReLU(s*(s>=0 ? max_k z : min_k z) + t)
__global__ __launch_bounds__(256) void finalize_kernel(const float* __restrict__ zmax,
                                                       const float* __restrict__ zmin,
                                                       const float* __restrict__ sc2,
                                                       const float* __restrict__ sh2,
                                                       float* __restrict__ out, int Cmask) {
  int t = blockIdx.x * 256 + threadIdx.x;
  int c = t & Cmask;
  float scl = sc2[c];
  float v = (scl >= 0.f) ? zmax[t] : zmin[t];
  out[t] = fmaxf(fmaf(v, scl, sh2[c]), 0.f);
}

// ---------------------------------------------------------------- pooling
__global__ __launch_bounds__(256) void pool_kernel(const float* __restrict__ h,
                                                   float* __restrict__ pooled) {
  int b = blockIdx.x, c = threadIdx.x;
  float s = 0.f, mx = -INFINITY;
  for (int n = 0; n < NN; ++n) {
    float v = h[(size_t)(b * NN + n) * 256 + c];
    s += v;
    mx = fmaxf(mx, v);
  }
  pooled[b * 512 + c] = s * (1.f / 128.f);
  pooled[b * 512 + 256 + c] = mx;
}

// ---------------------------------------------------------------- FC layers
__global__ __launch_bounds__(256) void fc_gemm(const float* __restrict__ in,
                                               const float* __restrict__ W,
                                               const float* __restrict__ bias,
                                               float* __restrict__ outm, int Cin, int Cout) {
  int b = blockIdx.x, c = threadIdx.x;
  __shared__ float row[512];
  for (int i = c; i < Cin; i += blockDim.x) row[i] = in[b * Cin + i];
  __syncthreads();
  float acc = bias[c];
  for (int i = 0; i < Cin; ++i) acc = fmaf(row[i], W[i * Cout + c], acc);
  outm[b * Cout + c] = acc;
}

__global__ void bn_relu_rows(float* __restrict__ t, const float* __restrict__ g,
                             const float* __restrict__ beta, int rows, int C) {
  int c = threadIdx.x;
  float s = 0.f;
  for (int r = 0; r < rows; ++r) s += t[r * C + c];
  float mean = s / (float)rows;
  float v = 0.f;
  for (int r = 0; r < rows; ++r) {
    float d = t[r * C + c] - mean;
    v = fmaf(d, d, v);
  }
  v /= (float)rows;
  float scl = g[c] * rsqrtf(v + 1e-5f);
  float shf = beta[c] - mean * scl;
  for (int r = 0; r < rows; ++r)
    t[r * C + c] = fmaxf(fmaf(t[r * C + c], scl, shf), 0.f);
}

__global__ __launch_bounds__(256) void fc3_kernel(const float* __restrict__ t2,
                                                  const float* __restrict__ W,
                                                  const float* __restrict__ bias,
                                                  float* __restrict__ out) {
  int t = threadIdx.x;
  int b = t >> 1, j = t & 1;
  float acc = bias[j];
  for (int r = 0; r < 128; ++r) acc = fmaf(t2[b * 128 + r], W[r * 2 + j], acc);
  out[t] = acc;
}

// ---------------------------------------------------------------- per-layer driver

struct LayerPtrs {
  int* idx; float *p, *q, *zmx, *zmn, *stats;
  u16 *Wh, *Wl;
};

template<int C>
static void run_edgeconv(const float* xin, int Cin,
                         const float* W1, const float* b1, const float* g1, const float* e1,
                         const float* W2, const float* b2, const float* g2, const float* e2,
                         float* hout, const LayerPtrs& L, hipStream_t stream) {
  float* s1 = L.stats;
  float* ss1 = L.stats + 256;
  float* s2 = L.stats + 512;
  float* ss2 = L.stats + 768;
  float* sc1 = L.stats + 1024;
  float* sh1 = L.stats + 1280;
  float* sc2 = L.stats + 1536;
  float* sh2 = L.stats + 1792;

  (void)hipMemsetAsync(L.stats, 0, 4 * 256 * sizeof(float), stream);
  knn_kernel<<<dim3(MNODE), dim3(64), 0, stream>>>(xin, Cin, L.idx);
  node_gemm<<<dim3(MNODE / 8), dim3(C), 0, stream>>>(xin, W1, L.p, L.q, Cin, C);
  pack_w2<C><<<dim3((C * C + 255) / 256), dim3(256), 0, stream>>>(W2, L.Wh, L.Wl);
  edge_stats1<<<dim3(MNODE / 16), dim3(C), 0, stream>>>(L.p, L.q, b1, L.idx, s1, ss1, C);
  bn_params<<<dim3(1), dim3(C), 0, stream>>>(s1, ss1, g1, e1, b1, (float)MEDGE, sc1, sh1);
  edge_gemm2_mfma<C><<<dim3(MNODE / 8), dim3(64), 0, stream>>>(
      L.p, L.q, L.idx, sc1, sh1, L.Wh, L.Wl, b2, L.zmx, L.zmn, s2, ss2);
  bn_params<<<dim3(1), dim3(C), 0, stream>>>(s2, ss2, g2, e2, nullptr, (float)MEDGE, sc2, sh2);
  finalize_kernel<<<dim3(MNODE * C / 256), dim3(256), 0, stream>>>(L.zmx, L.zmn, sc2, sh2,
                                                                   hout, C - 1);
}

// ---------------------------------------------------------------- launch

extern "C" void kernel_launch(void* const* d_in, const int* in_sizes, int n_in,
                              void* d_out, int out_size, void* d_ws, size_t ws_size,
                              hipStream_t stream) {
  const float* x   = (const float*)d_in[0];
  const float* w11 = (const float*)d_in[1];
  const float* b11 = (const float*)d_in[2];
  const float* g11 = (const float*)d_in[3];
  const float* e11 = (const float*)d_in[4];
  const float* w12 = (const float*)d_in[5];
  const float* b12 = (const float*)d_in[6];
  const float* g12 = (const float*)d_in[7];
  const float* e12 = (const float*)d_in[8];
  const float* w21 = (const float*)d_in[9];
  const float* b21 = (const float*)d_in[10];
  const float* g21 = (const float*)d_in[11];
  const float* e21 = (const float*)d_in[12];
  const float* w22 = (const float*)d_in[13];
  const float* b22 = (const float*)d_in[14];
  const float* g22 = (const float*)d_in[15];
  const float* e22 = (const float*)d_in[16];
  const float* w31 = (const float*)d_in[17];
  const float* b31 = (const float*)d_in[18];
  const float* g31 = (const float*)d_in[19];
  const float* e31 = (const float*)d_in[20];
  const float* w32 = (const float*)d_in[21];
  const float* b32 = (const float*)d_in[22];
  const float* g32 = (const float*)d_in[23];
  const float* e32 = (const float*)d_in[24];
  const float* fw1 = (const float*)d_in[25];
  const float* fb1 = (const float*)d_in[26];
  const float* fg1 = (const float*)d_in[27];
  const float* fe1 = (const float*)d_in[28];
  const float* fw2 = (const float*)d_in[29];
  const float* fb2 = (const float*)d_in[30];
  const float* fg2 = (const float*)d_in[31];
  const float* fe2 = (const float*)d_in[32];
  const float* fw3 = (const float*)d_in[33];
  const float* fb3 = (const float*)d_in[34];

  char* wsb = (char*)d_ws;
  size_t o = 0;
  auto alloc = [&](size_t bytes) -> void* {
    void* r = wsb + o;
    o += (bytes + 255) & ~(size_t)255;
    return r;
  };
  LayerPtrs L;
  L.idx   = (int*)  alloc((size_t)MNODE * KK * sizeof(int));
  L.p     = (float*)alloc((size_t)MNODE * 256 * sizeof(float));
  L.q     = (float*)alloc((size_t)MNODE * 256 * sizeof(float));
  L.zmx   = (float*)alloc((size_t)MNODE * 256 * sizeof(float));
  L.zmn   = (float*)alloc((size_t)MNODE * 256 * sizeof(float));
  L.stats = (float*)alloc(8 * 256 * sizeof(float));
  L.Wh    = (u16*)  alloc((size_t)256 * 256 * sizeof(u16));
  L.Wl    = (u16*)  alloc((size_t)256 * 256 * sizeof(u16));
  float* h1buf  = (float*)alloc((size_t)MNODE * 64 * sizeof(float));
  float* h2buf  = (float*)alloc((size_t)MNODE * 128 * sizeof(float));
  float* h3buf  = (float*)alloc((size_t)MNODE * 256 * sizeof(float));
  float* pooled = (float*)alloc(128 * 512 * sizeof(float));
  float* t1     = (float*)alloc(128 * 256 * sizeof(float));
  float* t2     = (float*)alloc(128 * 128 * sizeof(float));

  run_edgeconv<64 >(x,     6,   w11, b11, g11, e11, w12, b12, g12, e12, h1buf, L, stream);
  run_edgeconv<128>(h1buf, 64,  w21, b21, g21, e21, w22, b22, g22, e22, h2buf, L, stream);
  run_edgeconv<256>(h2buf, 128, w31, b31, g31, e31, w32, b32, g32, e32, h3buf, L, stream);

  pool_kernel<<<dim3(BB), dim3(256), 0, stream>>>(h3buf, pooled);
  fc_gemm<<<dim3(BB), dim3(256), 0, stream>>>(pooled, fw1, fb1, t1, 512, 256);
  bn_relu_rows<<<dim3(1), dim3(256), 0, stream>>>(t1, fg1, fe1, 128, 256);
  fc_gemm<<<dim3(BB), dim3(128), 0, stream>>>(t1, fw2, fb2, t2, 256, 128);
  bn_relu_rows<<<dim3(1), dim3(128), 0, stream>>>(t2, fg2, fe2, 128, 128);
  fc3_kernel<<<dim3(1), dim3(256), 0, stream>>>(t2, fw3, fb3, (float*)d_out);
}

// Round 4
// 1655.336 us; speedup vs baseline: 1.3973x; 1.1990x over previous
//
#include <hip/hip_runtime.h>
#include <math.h>

#define BB 128
#define NN 128
#define KK 16
#define MEDGE (BB*NN*KK)   // 262144 edges
#define MNODE (BB*NN)      // 16384 nodes

typedef __bf16 bf16x8 __attribute__((ext_vector_type(8)));
typedef float  floatx16 __attribute__((ext_vector_type(16)));
typedef unsigned short u16;
typedef u16 ushort8_alias __attribute__((ext_vector_type(8)));

// ---------------------------------------------------------------- utilities

__device__ __forceinline__ unsigned ord32(float f) {
  unsigned u = __float_as_uint(f);
  return (u & 0x80000000u) ? ~u : (u | 0x80000000u);
}

__device__ __forceinline__ unsigned long long shfl_xor_u64(unsigned long long v, int m) {
  unsigned lo = (unsigned)(v & 0xffffffffull);
  unsigned hi = (unsigned)(v >> 32);
  lo = __shfl_xor(lo, m, 64);
  hi = __shfl_xor(hi, m, 64);
  return (((unsigned long long)hi) << 32) | (unsigned long long)lo;
}

// ---------------------------------------------------------------- kNN
__global__ __launch_bounds__(64) void knn_kernel(const float* __restrict__ x, int C,
                                                 int* __restrict__ idx) {
  int bn = blockIdx.x;
  int b = bn >> 7, n = bn & 127;
  int lane = threadIdx.x;
  const float* xb = x + (size_t)b * NN * C;
  __shared__ float xn[256];
  for (int c = lane; c < C; c += 64) xn[c] = xb[n * C + c];
  __syncthreads();
  float sqn = 0.f;
  for (int c = 0; c < C; ++c) sqn = fmaf(xn[c], xn[c], sqn);

  unsigned long long key[2];
#pragma unroll
  for (int t = 0; t < 2; ++t) {
    int m = lane + 64 * t;
    const float* xm = xb + (size_t)m * C;
    float dot = 0.f, sqm = 0.f;
    for (int c = 0; c < C; ++c) {
      float v = xm[c];
      dot = fmaf(xn[c], v, dot);
      sqm = fmaf(v, v, sqm);
    }
    float d = sqn - 2.f * dot + sqm;
    key[t] = (((unsigned long long)ord32(d)) << 32) | (unsigned)m;
  }

  int* out = idx + (size_t)bn * KK;
  for (int r = 0; r < KK; ++r) {
    unsigned long long mk = key[0] < key[1] ? key[0] : key[1];
#pragma unroll
    for (int off = 32; off > 0; off >>= 1) {
      unsigned long long o = shfl_xor_u64(mk, off);
      if (o < mk) mk = o;
    }
    int wm = (int)(mk & 0xffffffffu);
    if (lane == 0) out[r] = wm;
    if ((wm & 63) == lane) key[wm >> 6] = ~0ull;
  }
}

// ---------------------------------------------------------------- node GEMM
// p = x @ (W1_top - W1_bot),  q = x @ W1_bot    (W1 is [2*Cin, Cout] row-major)
__global__ __launch_bounds__(256) void node_gemm(const float* __restrict__ x,
                                                 const float* __restrict__ W,
                                                 float* __restrict__ p, float* __restrict__ q,
                                                 int Cin, int Cout) {
  int c = threadIdx.x;
  __shared__ float xr[128];
  for (int r = 0; r < 8; ++r) {
    int row = blockIdx.x * 8 + r;
    __syncthreads();
    for (int i = c; i < Cin; i += blockDim.x) xr[i] = x[(size_t)row * Cin + i];
    __syncthreads();
    float a = 0.f, qv = 0.f;
    for (int i = 0; i < Cin; ++i) {
      float xv = xr[i];
      a  = fmaf(xv, W[i * Cout + c], a);
      qv = fmaf(xv, W[(Cin + i) * Cout + c], qv);
    }
    p[(size_t)row * Cout + c] = a - qv;
    q[(size_t)row * Cout + c] = qv;
  }
}

// ---------------------------------------------------------------- BN1 stats over edges
__global__ __launch_bounds__(256) void edge_stats1(const float* __restrict__ p,
                                                   const float* __restrict__ q,
                                                   const float* __restrict__ b1,
                                                   const int* __restrict__ idx,
                                                   float* __restrict__ s1, float* __restrict__ ss1,
                                                   int C) {
  int c = threadIdx.x;
  float s = 0.f, ss = 0.f;
  float bias = b1[c];
  for (int ni = 0; ni < 16; ++ni) {
    int bn = blockIdx.x * 16 + ni;
    int b = bn >> 7;
    const int* id = idx + (size_t)bn * KK;
    float pv = p[(size_t)bn * C + c] + bias;
#pragma unroll
    for (int k = 0; k < KK; ++k) {
      int j = id[k];
      float y = pv + q[(size_t)(b * NN + j) * C + c];
      s += y;
      ss = fmaf(y, y, ss);
    }
  }
  atomicAdd(&s1[c], s);
  atomicAdd(&ss1[c], ss);
}

// ---------------------------------------------------------------- BN params
// shift = beta - mean*scale (+ scale*bias folded in when bias != null)
__global__ void bn_params(const float* __restrict__ s, const float* __restrict__ ss,
                          const float* __restrict__ g, const float* __restrict__ beta,
                          const float* __restrict__ bias,
                          float M, float* __restrict__ scale, float* __restrict__ shift) {
  int c = threadIdx.x;
  float mean = s[c] / M;
  float var = ss[c] / M - mean * mean;
  if (var < 0.f) var = 0.f;
  float sc = g[c] * rsqrtf(var + 1e-5f);
  scale[c] = sc;
  float sh = beta[c] - mean * sc;
  if (bias) sh += sc * bias[c];
  shift[c] = sh;
}

// ---------------------------------------------------------------- W2 packing
// Fragment order for v_mfma_f32_32x32x16_bf16 B operand:
// B[k][n], n = lane&31, k = (lane>>5)*8 + j. Flat index ((kt*NT+nt)*64+lane)*8+j.
__device__ __forceinline__ u16 bf16_rne_bits(float x) {
  unsigned u = __float_as_uint(x);
  return (u16)((u + 0x7FFF + ((u >> 16) & 1)) >> 16);
}

template<int C>
__global__ __launch_bounds__(256) void pack_w2(const float* __restrict__ W,
                                               u16* __restrict__ Wh, u16* __restrict__ Wl) {
  int t = blockIdx.x * 256 + threadIdx.x;
  if (t >= C * C) return;
  constexpr int NT = C / 32;
  int j = t & 7, lane = (t >> 3) & 63, ktnt = t >> 9;
  int nt = ktnt % NT, kt = ktnt / NT;
  int row = kt * 16 + (lane >> 5) * 8 + j;
  int col = nt * 32 + (lane & 31);
  float w = W[row * C + col];
  u16 h = bf16_rne_bits(w);
  float hf = __uint_as_float(((unsigned)h) << 16);
  Wh[t] = h;
  Wl[t] = bf16_rne_bits(w - hf);
}

// ---------------------------------------------------------------- MFMA edge GEMM2
// One wave = one M-tile (2 nodes x 16 neighbors = 32 edges), FULL-N accumulators
// (NT tiles of 32 cols) held across the K loop. Per k-tile: build A hi/lo bf16
// fragments in registers (live only this iteration), stream bh/bl from packed
// W2 (L2), 3 MFMAs per n-tile: Ah*Bh + Al*Bh + Ah*Bl. Single K pass, no spill.
// Epilogue: per-node max/min over k + BN2 sum/sumsq straight from acc regs.
template<int C>
__global__ __launch_bounds__(256, 2) void edge_gemm2_mfma(
    const float* __restrict__ p, const float* __restrict__ q,
    const int* __restrict__ idx,
    const float* __restrict__ sc1, const float* __restrict__ sh1,  // bias1 folded into sh1
    const u16* __restrict__ Wh, const u16* __restrict__ Wl,
    const float* __restrict__ b2,
    float* __restrict__ zmax, float* __restrict__ zmin,
    float* __restrict__ s2, float* __restrict__ ss2) {
  constexpr int KT = C / 16, NT = C / 32;
  int lane = threadIdx.x & 63;
  int wv = threadIdx.x >> 6;
  int m = lane & 31, lh = lane >> 5;

  int mtile = blockIdx.x * 4 + wv;
  int nodeBase = mtile * 2;

  // edge owned by this lane's A-row: node = nodeBase + (m>>4), neighbor m&15
  int nd = nodeBase + (m >> 4);
  int bg = nd >> 7;
  int j = idx[nd * KK + (m & 15)];
  const float* pr = p + (size_t)nd * C;
  const float* qr = q + (size_t)(bg * NN + j) * C;

  floatx16 acc[NT];
#pragma unroll
  for (int nt = 0; nt < NT; ++nt) {
    float bv = b2[nt * 32 + m];
#pragma unroll
    for (int r = 0; r < 16; ++r) acc[nt][r] = bv;
  }

  for (int kt = 0; kt < KT; ++kt) {
    int c0 = kt * 16 + lh * 8;
    float4 pa = *(const float4*)(pr + c0);
    float4 pb = *(const float4*)(pr + c0 + 4);
    float4 qa = *(const float4*)(qr + c0);
    float4 qb = *(const float4*)(qr + c0 + 4);
    float4 sa = *(const float4*)(sc1 + c0);
    float4 sb = *(const float4*)(sc1 + c0 + 4);
    float4 ta = *(const float4*)(sh1 + c0);
    float4 tb = *(const float4*)(sh1 + c0 + 4);
    float hv[8];
    hv[0] = fmaxf(fmaf(pa.x + qa.x, sa.x, ta.x), 0.f);
    hv[1] = fmaxf(fmaf(pa.y + qa.y, sa.y, ta.y), 0.f);
    hv[2] = fmaxf(fmaf(pa.z + qa.z, sa.z, ta.z), 0.f);
    hv[3] = fmaxf(fmaf(pa.w + qa.w, sa.w, ta.w), 0.f);
    hv[4] = fmaxf(fmaf(pb.x + qb.x, sb.x, tb.x), 0.f);
    hv[5] = fmaxf(fmaf(pb.y + qb.y, sb.y, tb.y), 0.f);
    hv[6] = fmaxf(fmaf(pb.z + qb.z, sb.z, tb.z), 0.f);
    hv[7] = fmaxf(fmaf(pb.w + qb.w, sb.w, tb.w), 0.f);
    bf16x8 ah, al;
#pragma unroll
    for (int t = 0; t < 8; ++t) {
      __bf16 hb = (__bf16)hv[t];
      float lo = hv[t] - (float)hb;
      ah[t] = hb;
      al[t] = (__bf16)lo;
    }

#pragma unroll
    for (int nt = 0; nt < NT; ++nt) {
      int e0 = (kt * NT + nt) * 64 + lane;  // ushort8 element index
      bf16x8 bh = __builtin_bit_cast(bf16x8, ((const ushort8_alias*)Wh)[e0]);
      bf16x8 bl = __builtin_bit_cast(bf16x8, ((const ushort8_alias*)Wl)[e0]);
      acc[nt] = __builtin_amdgcn_mfma_f32_32x32x16_bf16(ah, bh, acc[nt], 0, 0, 0);
      acc[nt] = __builtin_amdgcn_mfma_f32_32x32x16_bf16(al, bh, acc[nt], 0, 0, 0);
      acc[nt] = __builtin_amdgcn_mfma_f32_32x32x16_bf16(ah, bl, acc[nt], 0, 0, 0);
    }
  }

  // ---- epilogue: acc row = (r&3)+8*(r>>2)+4*lh, col = lane&31.
  // regs 0..7 -> rows 0..15 (nodeBase's 16 neighbors), regs 8..15 -> nodeBase+1.
#pragma unroll
  for (int nt = 0; nt < NT; ++nt) {
    float s = 0.f, ss = 0.f;
    float mxA = -INFINITY, mnA = INFINITY, mxB = -INFINITY, mnB = INFINITY;
#pragma unroll
    for (int r = 0; r < 8; ++r) {
      float z = acc[nt][r];
      s += z; ss = fmaf(z, z, ss);
      mxA = fmaxf(mxA, z); mnA = fminf(mnA, z);
    }
#pragma unroll
    for (int r = 8; r < 16; ++r) {
      float z = acc[nt][r];
      s += z; ss = fmaf(z, z, ss);
      mxB = fmaxf(mxB, z); mnB = fminf(mnB, z);
    }
    mxA = fmaxf(mxA, __shfl_xor(mxA, 32)); mnA = fminf(mnA, __shfl_xor(mnA, 32));
    mxB = fmaxf(mxB, __shfl_xor(mxB, 32)); mnB = fminf(mnB, __shfl_xor(mnB, 32));
    float sw = s + __shfl_xor(s, 32);
    float ssw = ss + __shfl_xor(ss, 32);
    if (lane < 32) {
      int col = nt * 32 + m;
      zmax[(size_t)nodeBase * C + col] = mxA;
      zmin[(size_t)nodeBase * C + col] = mnA;
      zmax[(size_t)(nodeBase + 1) * C + col] = mxB;
      zmin[(size_t)(nodeBase + 1) * C + col] = mnB;
      atomicAdd(&s2[col], sw);
      atomicAdd(&ss2[col], ssw);
    }
  }
}

// ---------------------------------------------------------------- finalize
// max_k ReLU(s*z+t) = ReLU(s*(s>=0 ? max_k z : min_k z) + t)
__global__ __launch_bounds__(256) void finalize_kernel(const float* __restrict__ zmax,
                                                       const float* __restrict__ zmin,
                                                       const float* __restrict__ sc2,
                                                       const float* __restrict__ sh2,
                                                       float* __restrict__ out, int Cmask) {
  int t = blockIdx.x * 256 + threadIdx.x;
  int c = t & Cmask;
  float scl = sc2[c];
  float v = (scl >= 0.f) ? zmax[t] : zmin[t];
  out[t] = fmaxf(fmaf(v, scl, sh2[c]), 0.f);
}

// ---------------------------------------------------------------- pooling
__global__ __launch_bounds__(256) void pool_kernel(const float* __restrict__ h,
                                                   float* __restrict__ pooled) {
  int b = blockIdx.x, c = threadIdx.x;
  float s = 0.f, mx = -INFINITY;
  for (int n = 0; n < NN; ++n) {
    float v = h[(size_t)(b * NN + n) * 256 + c];
    s += v;
    mx = fmaxf(mx, v);
  }
  pooled[b * 512 + c] = s * (1.f / 128.f);
  pooled[b * 512 + 256 + c] = mx;
}

// ---------------------------------------------------------------- FC layers
__global__ __launch_bounds__(256) void fc_gemm(const float* __restrict__ in,
                                               const float* __restrict__ W,
                                               const float* __restrict__ bias,
                                               float* __restrict__ outm, int Cin, int Cout) {
  int b = blockIdx.x, c = threadIdx.x;
  __shared__ float row[512];
  for (int i = c; i < Cin; i += blockDim.x) row[i] = in[b * Cin + i];
  __syncthreads();
  float acc = bias[c];
  for (int i = 0; i < Cin; ++i) acc = fmaf(row[i], W[i * Cout + c], acc);
  outm[b * Cout + c] = acc;
}

__global__ void bn_relu_rows(float* __restrict__ t, const float* __restrict__ g,
                             const float* __restrict__ beta, int rows, int C) {
  int c = threadIdx.x;
  float s = 0.f;
  for (int r = 0; r < rows; ++r) s += t[r * C + c];
  float mean = s / (float)rows;
  float v = 0.f;
  for (int r = 0; r < rows; ++r) {
    float d = t[r * C + c] - mean;
    v = fmaf(d, d, v);
  }
  v /= (float)rows;
  float scl = g[c] * rsqrtf(v + 1e-5f);
  float shf = beta[c] - mean * scl;
  for (int r = 0; r < rows; ++r)
    t[r * C + c] = fmaxf(fmaf(t[r * C + c], scl, shf), 0.f);
}

__global__ __launch_bounds__(256) void fc3_kernel(const float* __restrict__ t2,
                                                  const float* __restrict__ W,
                                                  const float* __restrict__ bias,
                                                  float* __restrict__ out) {
  int t = threadIdx.x;
  int b = t >> 1, j = t & 1;
  float acc = bias[j];
  for (int r = 0; r < 128; ++r) acc = fmaf(t2[b * 128 + r], W[r * 2 + j], acc);
  out[t] = acc;
}

// ---------------------------------------------------------------- per-layer driver

struct LayerPtrs {
  int* idx; float *p, *q, *zmx, *zmn, *stats;
  u16 *Wh, *Wl;
};

template<int C>
static void run_edgeconv(const float* xin, int Cin,
                         const float* W1, const float* b1, const float* g1, const float* e1,
                         const float* W2, const float* b2, const float* g2, const float* e2,
                         float* hout, const LayerPtrs& L, hipStream_t stream) {
  float* s1 = L.stats;
  float* ss1 = L.stats + 256;
  float* s2 = L.stats + 512;
  float* ss2 = L.stats + 768;
  float* sc1 = L.stats + 1024;
  float* sh1 = L.stats + 1280;
  float* sc2 = L.stats + 1536;
  float* sh2 = L.stats + 1792;

  (void)hipMemsetAsync(L.stats, 0, 4 * 256 * sizeof(float), stream);
  knn_kernel<<<dim3(MNODE), dim3(64), 0, stream>>>(xin, Cin, L.idx);
  node_gemm<<<dim3(MNODE / 8), dim3(C), 0, stream>>>(xin, W1, L.p, L.q, Cin, C);
  pack_w2<C><<<dim3((C * C + 255) / 256), dim3(256), 0, stream>>>(W2, L.Wh, L.Wl);
  edge_stats1<<<dim3(MNODE / 16), dim3(C), 0, stream>>>(L.p, L.q, b1, L.idx, s1, ss1, C);
  bn_params<<<dim3(1), dim3(C), 0, stream>>>(s1, ss1, g1, e1, b1, (float)MEDGE, sc1, sh1);
  edge_gemm2_mfma<C><<<dim3(MNODE / 8), dim3(256), 0, stream>>>(
      L.p, L.q, L.idx, sc1, sh1, L.Wh, L.Wl, b2, L.zmx, L.zmn, s2, ss2);
  bn_params<<<dim3(1), dim3(C), 0, stream>>>(s2, ss2, g2, e2, nullptr, (float)MEDGE, sc2, sh2);
  finalize_kernel<<<dim3(MNODE * C / 256), dim3(256), 0, stream>>>(L.zmx, L.zmn, sc2, sh2,
                                                                   hout, C - 1);
}

// ---------------------------------------------------------------- launch

extern "C" void kernel_launch(void* const* d_in, const int* in_sizes, int n_in,
                              void* d_out, int out_size, void* d_ws, size_t ws_size,
                              hipStream_t stream) {
  const float* x   = (const float*)d_in[0];
  const float* w11 = (const float*)d_in[1];
  const float* b11 = (const float*)d_in[2];
  const float* g11 = (const float*)d_in[3];
  const float* e11 = (const float*)d_in[4];
  const float* w12 = (const float*)d_in[5];
  const float* b12 = (const float*)d_in[6];
  const float* g12 = (const float*)d_in[7];
  const float* e12 = (const float*)d_in[8];
  const float* w21 = (const float*)d_in[9];
  const float* b21 = (const float*)d_in[10];
  const float* g21 = (const float*)d_in[11];
  const float* e21 = (const float*)d_in[12];
  const float* w22 = (const float*)d_in[13];
  const float* b22 = (const float*)d_in[14];
  const float* g22 = (const float*)d_in[15];
  const float* e22 = (const float*)d_in[16];
  const float* w31 = (const float*)d_in[17];
  const float* b31 = (const float*)d_in[18];
  const float* g31 = (const float*)d_in[19];
  const float* e31 = (const float*)d_in[20];
  const float* w32 = (const float*)d_in[21];
  const float* b32 = (const float*)d_in[22];
  const float* g32 = (const float*)d_in[23];
  const float* e32 = (const float*)d_in[24];
  const float* fw1 = (const float*)d_in[25];
  const float* fb1 = (const float*)d_in[26];
  const float* fg1 = (const float*)d_in[27];
  const float* fe1 = (const float*)d_in[28];
  const float* fw2 = (const float*)d_in[29];
  const float* fb2 = (const float*)d_in[30];
  const float* fg2 = (const float*)d_in[31];
  const float* fe2 = (const float*)d_in[32];
  const float* fw3 = (const float*)d_in[33];
  const float* fb3 = (const float*)d_in[34];

  char* wsb = (char*)d_ws;
  size_t o = 0;
  auto alloc = [&](size_t bytes) -> void* {
    void* r = wsb + o;
    o += (bytes + 255) & ~(size_t)255;
    return r;
  };
  LayerPtrs L;
  L.idx   = (int*)  alloc((size_t)MNODE * KK * sizeof(int));
  L.p     = (float*)alloc((size_t)MNODE * 256 * sizeof(float));
  L.q     = (float*)alloc((size_t)MNODE * 256 * sizeof(float));
  L.zmx   = (float*)alloc((size_t)MNODE * 256 * sizeof(float));
  L.zmn   = (float*)alloc((size_t)MNODE * 256 * sizeof(float));
  L.stats = (float*)alloc(8 * 256 * sizeof(float));
  L.Wh    = (u16*)  alloc((size_t)256 * 256 * sizeof(u16));
  L.Wl    = (u16*)  alloc((size_t)256 * 256 * sizeof(u16));
  float* h1buf  = (float*)alloc((size_t)MNODE * 64 * sizeof(float));
  float* h2buf  = (float*)alloc((size_t)MNODE * 128 * sizeof(float));
  float* h3buf  = (float*)alloc((size_t)MNODE * 256 * sizeof(float));
  float* pooled = (float*)alloc(128 * 512 * sizeof(float));
  float* t1     = (float*)alloc(128 * 256 * sizeof(float));
  float* t2     = (float*)alloc(128 * 128 * sizeof(float));

  run_edgeconv<64 >(x,     6,   w11, b11, g11, e11, w12, b12, g12, e12, h1buf, L, stream);
  run_edgeconv<128>(h1buf, 64,  w21, b21, g21, e21, w22, b22, g22, e22, h2buf, L, stream);
  run_edgeconv<256>(h2buf, 128, w31, b31, g31, e31, w32, b32, g32, e32, h3buf, L, stream);

  pool_kernel<<<dim3(BB), dim3(256), 0, stream>>>(h3buf, pooled);
  fc_gemm<<<dim3(BB), dim3(256), 0, stream>>>(pooled, fw1, fb1, t1, 512, 256);
  bn_relu_rows<<<dim3(1), dim3(256), 0, stream>>>(t1, fg1, fe1, 128, 256);
  fc_gemm<<<dim3(BB), dim3(128), 0, stream>>>(t1, fw2, fb2, t2, 256, 128);
  bn_relu_rows<<<dim3(1), dim3(128), 0, stream>>>(t2, fg2, fe2, 128, 128);
  fc3_kernel<<<dim3(1), dim3(256), 0, stream>>>(t2, fw3, fb3, (float*)d_out);
}

// Round 5
// 1537.508 us; speedup vs baseline: 1.5044x; 1.0766x over previous
//
#include <hip/hip_runtime.h>
#include <math.h>

#define BB 128
#define NN 128
#define KK 16
#define MEDGE (BB*NN*KK)   // 262144 edges
#define MNODE (BB*NN)      // 16384 nodes

typedef __bf16 bf16x8 __attribute__((ext_vector_type(8)));
typedef float  floatx4 __attribute__((ext_vector_type(4)));
typedef unsigned short u16;
typedef u16 ushort8_alias __attribute__((ext_vector_type(8)));

// ---------------------------------------------------------------- utilities

__device__ __forceinline__ unsigned ord32(float f) {
  unsigned u = __float_as_uint(f);
  return (u & 0x80000000u) ? ~u : (u | 0x80000000u);
}

__device__ __forceinline__ unsigned long long shfl_xor_u64(unsigned long long v, int m) {
  unsigned lo = (unsigned)(v & 0xffffffffull);
  unsigned hi = (unsigned)(v >> 32);
  lo = __shfl_xor(lo, m, 64);
  hi = __shfl_xor(hi, m, 64);
  return (((unsigned long long)hi) << 32) | (unsigned long long)lo;
}

// XCD-aware swizzle: 4096 blocks, 4 nodes/block. Blocks of the same batch b
// share (blockIdx % 8) -> same XCD -> q-slab (128 KB) stays hot in that L2.
__device__ __forceinline__ int swiz_node(int blk, int wv) {
  int slot = blk >> 3;
  int b = (blk & 7) + 8 * (slot >> 5);
  int within = slot & 31;
  return b * NN + within * 4 + wv;
}

// ---------------------------------------------------------------- kNN
__global__ __launch_bounds__(64) void knn_kernel(const float* __restrict__ x, int C,
                                                 int* __restrict__ idx) {
  int bn = blockIdx.x;
  int b = bn >> 7, n = bn & 127;
  int lane = threadIdx.x;
  const float* xb = x + (size_t)b * NN * C;
  __shared__ float xn[256];
  for (int c = lane; c < C; c += 64) xn[c] = xb[n * C + c];
  __syncthreads();
  float sqn = 0.f;
  for (int c = 0; c < C; ++c) sqn = fmaf(xn[c], xn[c], sqn);

  unsigned long long key[2];
#pragma unroll
  for (int t = 0; t < 2; ++t) {
    int m = lane + 64 * t;
    const float* xm = xb + (size_t)m * C;
    float dot = 0.f, sqm = 0.f;
    for (int c = 0; c < C; ++c) {
      float v = xm[c];
      dot = fmaf(xn[c], v, dot);
      sqm = fmaf(v, v, sqm);
    }
    float d = sqn - 2.f * dot + sqm;
    key[t] = (((unsigned long long)ord32(d)) << 32) | (unsigned)m;
  }

  int* out = idx + (size_t)bn * KK;
  for (int r = 0; r < KK; ++r) {
    unsigned long long mk = key[0] < key[1] ? key[0] : key[1];
#pragma unroll
    for (int off = 32; off > 0; off >>= 1) {
      unsigned long long o = shfl_xor_u64(mk, off);
      if (o < mk) mk = o;
    }
    int wm = (int)(mk & 0xffffffffu);
    if (lane == 0) out[r] = wm;
    if ((wm & 63) == lane) key[wm >> 6] = ~0ull;
  }
}

// ---------------------------------------------------------------- node GEMM
// p = x @ (W1_top - W1_bot),  q = x @ W1_bot    (W1 is [2*Cin, Cout] row-major)
__global__ __launch_bounds__(256) void node_gemm(const float* __restrict__ x,
                                                 const float* __restrict__ W,
                                                 float* __restrict__ p, float* __restrict__ q,
                                                 int Cin, int Cout) {
  int c = threadIdx.x;
  __shared__ float xr[128];
  for (int r = 0; r < 8; ++r) {
    int row = blockIdx.x * 8 + r;
    __syncthreads();
    for (int i = c; i < Cin; i += blockDim.x) xr[i] = x[(size_t)row * Cin + i];
    __syncthreads();
    float a = 0.f, qv = 0.f;
    for (int i = 0; i < Cin; ++i) {
      float xv = xr[i];
      a  = fmaf(xv, W[i * Cout + c], a);
      qv = fmaf(xv, W[(Cin + i) * Cout + c], qv);
    }
    p[(size_t)row * Cout + c] = a - qv;
    q[(size_t)row * Cout + c] = qv;
  }
}

// ---------------------------------------------------------------- BN1 stats (vectorized)
// One wave per node, float4 lanes; LDS block reduction then one atomic/channel.
template<int C>
__global__ __launch_bounds__(256) void edge_stats1v(const float* __restrict__ p,
                                                    const float* __restrict__ q,
                                                    const float* __restrict__ b1,
                                                    const int* __restrict__ idx,
                                                    float* __restrict__ s1,
                                                    float* __restrict__ ss1) {
  constexpr int G = C / 4;    // float4 groups per row
  constexpr int KL = 64 / G;  // k-lanes per wave (1,2,4)
  int tid = threadIdx.x, lane = tid & 63, wv = tid >> 6;
  int nd = swiz_node(blockIdx.x, wv);
  int b = nd >> 7;
  int g = lane % G, kl = lane / G;

  __shared__ float sS[C], sSS[C];
  if (tid < C) { sS[tid] = 0.f; sSS[tid] = 0.f; }
  __syncthreads();

  const float* pr = p + (size_t)nd * C;
  float4 pv = *(const float4*)(pr + g * 4);
  float4 bv = *(const float4*)(b1 + g * 4);
  pv.x += bv.x; pv.y += bv.y; pv.z += bv.z; pv.w += bv.w;
  float4 s = {0, 0, 0, 0}, ss = {0, 0, 0, 0};
  const int* id = idx + (size_t)nd * KK;
#pragma unroll
  for (int k0 = 0; k0 < KK; k0 += KL) {
    int j = id[k0 + kl];
    float4 q4 = *(const float4*)(q + (size_t)(b * NN + j) * C + g * 4);
    float y;
    y = pv.x + q4.x; s.x += y; ss.x = fmaf(y, y, ss.x);
    y = pv.y + q4.y; s.y += y; ss.y = fmaf(y, y, ss.y);
    y = pv.z + q4.z; s.z += y; ss.z = fmaf(y, y, ss.z);
    y = pv.w + q4.w; s.w += y; ss.w = fmaf(y, y, ss.w);
  }
#pragma unroll
  for (int off = G; off < 64; off <<= 1) {
    s.x += __shfl_xor(s.x, off); ss.x += __shfl_xor(ss.x, off);
    s.y += __shfl_xor(s.y, off); ss.y += __shfl_xor(ss.y, off);
    s.z += __shfl_xor(s.z, off); ss.z += __shfl_xor(ss.z, off);
    s.w += __shfl_xor(s.w, off); ss.w += __shfl_xor(ss.w, off);
  }
  if (kl == 0) {
    atomicAdd(&sS[g * 4 + 0], s.x); atomicAdd(&sSS[g * 4 + 0], ss.x);
    atomicAdd(&sS[g * 4 + 1], s.y); atomicAdd(&sSS[g * 4 + 1], ss.y);
    atomicAdd(&sS[g * 4 + 2], s.z); atomicAdd(&sSS[g * 4 + 2], ss.z);
    atomicAdd(&sS[g * 4 + 3], s.w); atomicAdd(&sSS[g * 4 + 3], ss.w);
  }
  __syncthreads();
  if (tid < C) {
    atomicAdd(&s1[tid], sS[tid]);
    atomicAdd(&ss1[tid], sSS[tid]);
  }
}

// ---------------------------------------------------------------- BN params
// shift = beta - mean*scale (+ scale*bias folded in when bias != null)
__global__ void bn_params(const float* __restrict__ s, const float* __restrict__ ss,
                          const float* __restrict__ g, const float* __restrict__ beta,
                          const float* __restrict__ bias,
                          float M, float* __restrict__ scale, float* __restrict__ shift) {
  int c = threadIdx.x;
  float mean = s[c] / M;
  float var = ss[c] / M - mean * mean;
  if (var < 0.f) var = 0.f;
  float sc = g[c] * rsqrtf(var + 1e-5f);
  scale[c] = sc;
  float sh = beta[c] - mean * sc;
  if (bias) sh += sc * bias[c];
  shift[c] = sh;
}

// ---------------------------------------------------------------- W2 packing (16x16x32)
// B operand of v_mfma_f32_16x16x32_bf16: B[k][n], n = lane&15, k = (lane>>4)*8+j.
__device__ __forceinline__ u16 bf16_rne_bits(float x) {
  unsigned u = __float_as_uint(x);
  return (u16)((u + 0x7FFF + ((u >> 16) & 1)) >> 16);
}

template<int C>
__global__ __launch_bounds__(256) void pack_w2(const float* __restrict__ W,
                                               u16* __restrict__ Wh, u16* __restrict__ Wl) {
  int t = blockIdx.x * 256 + threadIdx.x;
  if (t >= C * C) return;
  constexpr int NT = C / 16;
  int j = t & 7, lane = (t >> 3) & 63, tile = t >> 9;
  int nt = tile % NT, kt = tile / NT;
  int row = kt * 32 + (lane >> 4) * 8 + j;
  int col = nt * 16 + (lane & 15);
  float w = W[row * C + col];
  u16 h = bf16_rne_bits(w);
  float hf = __uint_as_float(((unsigned)h) << 16);
  Wh[t] = h;
  Wl[t] = bf16_rne_bits(w - hf);
}

// ---------------------------------------------------------------- MFMA edge GEMM2 (16x16x32)
// One wave = one node (16 neighbors = M). Full-N accumulators: NT tiles x 4 regs.
// Per k-tile (32 ch): build A hi/lo bf16 split in regs, stream packed W2 (L2),
// 3 MFMAs per n-tile (Ah*Bh + Al*Bh + Ah*Bl). Epilogue: max/min over k + BN2
// sum/sumsq from acc regs, LDS block reduction, one global atomic/channel/block.
template<int C>
__global__ __launch_bounds__(256, 3) void edge_gemm2_mfma16(
    const float* __restrict__ p, const float* __restrict__ q,
    const int* __restrict__ idx,
    const float* __restrict__ sc1, const float* __restrict__ sh1,  // bias1 folded into sh1
    const u16* __restrict__ Wh, const u16* __restrict__ Wl,
    const float* __restrict__ b2,
    float* __restrict__ zmax, float* __restrict__ zmin,
    float* __restrict__ s2, float* __restrict__ ss2) {
  constexpr int KT = C / 32, NT = C / 16;
  int tid = threadIdx.x, lane = tid & 63, wv = tid >> 6;
  int r = lane & 15, kseg = lane >> 4;

  __shared__ float sS[C], sSS[C];
  if (tid < C) { sS[tid] = 0.f; sSS[tid] = 0.f; }
  __syncthreads();

  int nd = swiz_node(blockIdx.x, wv);
  int b = nd >> 7;
  int j = idx[(size_t)nd * KK + r];
  const float* pr = p + (size_t)nd * C;
  const float* qr = q + (size_t)(b * NN + j) * C;

  floatx4 acc[NT];
#pragma unroll
  for (int nt = 0; nt < NT; ++nt) {
    float bv = b2[nt * 16 + r];
    acc[nt] = {bv, bv, bv, bv};
  }

#pragma unroll
  for (int kt = 0; kt < KT; ++kt) {
    int c0 = kt * 32 + kseg * 8;
    float4 pa = *(const float4*)(pr + c0);
    float4 pb = *(const float4*)(pr + c0 + 4);
    float4 qa = *(const float4*)(qr + c0);
    float4 qb = *(const float4*)(qr + c0 + 4);
    float4 sa = *(const float4*)(sc1 + c0);
    float4 sb = *(const float4*)(sc1 + c0 + 4);
    float4 ta = *(const float4*)(sh1 + c0);
    float4 tb = *(const float4*)(sh1 + c0 + 4);
    float hv[8];
    hv[0] = fmaxf(fmaf(pa.x + qa.x, sa.x, ta.x), 0.f);
    hv[1] = fmaxf(fmaf(pa.y + qa.y, sa.y, ta.y), 0.f);
    hv[2] = fmaxf(fmaf(pa.z + qa.z, sa.z, ta.z), 0.f);
    hv[3] = fmaxf(fmaf(pa.w + qa.w, sa.w, ta.w), 0.f);
    hv[4] = fmaxf(fmaf(pb.x + qb.x, sb.x, tb.x), 0.f);
    hv[5] = fmaxf(fmaf(pb.y + qb.y, sb.y, tb.y), 0.f);
    hv[6] = fmaxf(fmaf(pb.z + qb.z, sb.z, tb.z), 0.f);
    hv[7] = fmaxf(fmaf(pb.w + qb.w, sb.w, tb.w), 0.f);
    bf16x8 ah, al;
#pragma unroll
    for (int t = 0; t < 8; ++t) {
      __bf16 hb = (__bf16)hv[t];
      float lo = hv[t] - (float)hb;
      ah[t] = hb;
      al[t] = (__bf16)lo;
    }
#pragma unroll
    for (int nt = 0; nt < NT; ++nt) {
      int e0 = (kt * NT + nt) * 64 + lane;
      bf16x8 bh = __builtin_bit_cast(bf16x8, ((const ushort8_alias*)Wh)[e0]);
      bf16x8 bl = __builtin_bit_cast(bf16x8, ((const ushort8_alias*)Wl)[e0]);
      acc[nt] = __builtin_amdgcn_mfma_f32_16x16x32_bf16(ah, bh, acc[nt], 0, 0, 0);
      acc[nt] = __builtin_amdgcn_mfma_f32_16x16x32_bf16(al, bh, acc[nt], 0, 0, 0);
      acc[nt] = __builtin_amdgcn_mfma_f32_16x16x32_bf16(ah, bl, acc[nt], 0, 0, 0);
    }
  }

  // ---- epilogue: C/D layout col = lane&15, row = (lane>>4)*4 + reg (row = neighbor).
#pragma unroll
  for (int nt = 0; nt < NT; ++nt) {
    float s = 0.f, ss = 0.f, mx = -INFINITY, mn = INFINITY;
#pragma unroll
    for (int g = 0; g < 4; ++g) {
      float z = acc[nt][g];
      s += z; ss = fmaf(z, z, ss);
      mx = fmaxf(mx, z); mn = fminf(mn, z);
    }
    mx = fmaxf(mx, __shfl_xor(mx, 16)); mn = fminf(mn, __shfl_xor(mn, 16));
    s += __shfl_xor(s, 16); ss += __shfl_xor(ss, 16);
    mx = fmaxf(mx, __shfl_xor(mx, 32)); mn = fminf(mn, __shfl_xor(mn, 32));
    s += __shfl_xor(s, 32); ss += __shfl_xor(ss, 32);
    if (kseg == 0) {
      int col = nt * 16 + r;
      zmax[(size_t)nd * C + col] = mx;
      zmin[(size_t)nd * C + col] = mn;
      atomicAdd(&sS[col], s);
      atomicAdd(&sSS[col], ss);
    }
  }
  __syncthreads();
  if (tid < C) {
    atomicAdd(&s2[tid], sS[tid]);
    atomicAdd(&ss2[tid], sSS[tid]);
  }
}

// ---------------------------------------------------------------- finalize
// max_k ReLU(s*z+t) = ReLU(s*(s>=0 ? max_k z : min_k z) + t)
__global__ __launch_bounds__(256) void finalize_kernel(const float* __restrict__ zmax,
                                                       const float* __restrict__ zmin,
                                                       const float* __restrict__ sc2,
                                                       const float* __restrict__ sh2,
                                                       float* __restrict__ out, int Cmask) {
  int t = blockIdx.x * 256 + threadIdx.x;
  int c = t & Cmask;
  float scl = sc2[c];
  float v = (scl >= 0.f) ? zmax[t] : zmin[t];
  out[t] = fmaxf(fmaf(v, scl, sh2[c]), 0.f);
}

// ---------------------------------------------------------------- pooling
__global__ __launch_bounds__(256) void pool_kernel(const float* __restrict__ h,
                                                   float* __restrict__ pooled) {
  int b = blockIdx.x, c = threadIdx.x;
  float s = 0.f, mx = -INFINITY;
  for (int n = 0; n < NN; ++n) {
    float v = h[(size_t)(b * NN + n) * 256 + c];
    s += v;
    mx = fmaxf(mx, v);
  }
  pooled[b * 512 + c] = s * (1.f / 128.f);
  pooled[b * 512 + 256 + c] = mx;
}

// ---------------------------------------------------------------- FC tail (fused BN stats)
__global__ __launch_bounds__(256) void fc1_fused(const float* __restrict__ pooled,
                                                 const float* __restrict__ W,
                                                 const float* __restrict__ bias,
                                                 float* __restrict__ t1raw,
                                                 float* __restrict__ fs, float* __restrict__ fss) {
  int b = blockIdx.x, c = threadIdx.x;
  __shared__ float row[512];
  row[c] = pooled[b * 512 + c];
  row[c + 256] = pooled[b * 512 + 256 + c];
  __syncthreads();
  float acc = bias[c];
  for (int i = 0; i < 512; ++i) acc = fmaf(row[i], W[i * 256 + c], acc);
  t1raw[b * 256 + c] = acc;
  atomicAdd(&fs[c], acc);
  atomicAdd(&fss[c], acc * acc);
}

__global__ __launch_bounds__(256) void fc2_fused(const float* __restrict__ t1raw,
                                                 const float* __restrict__ sc,
                                                 const float* __restrict__ sh,
                                                 const float* __restrict__ W,
                                                 const float* __restrict__ bias,
                                                 float* __restrict__ t2raw,
                                                 float* __restrict__ gs, float* __restrict__ gss) {
  int b = blockIdx.x, c = threadIdx.x;
  __shared__ float row[256];
  row[c] = fmaxf(fmaf(t1raw[b * 256 + c], sc[c], sh[c]), 0.f);
  __syncthreads();
  if (c < 128) {
    float acc = bias[c];
    for (int i = 0; i < 256; ++i) acc = fmaf(row[i], W[i * 128 + c], acc);
    t2raw[b * 128 + c] = acc;
    atomicAdd(&gs[c], acc);
    atomicAdd(&gss[c], acc * acc);
  }
}

__global__ __launch_bounds__(256) void fc3_fused(const float* __restrict__ t2raw,
                                                 const float* __restrict__ sc,
                                                 const float* __restrict__ sh,
                                                 const float* __restrict__ W,
                                                 const float* __restrict__ bias,
                                                 float* __restrict__ out) {
  int t = threadIdx.x;  // 256 = 128 rows * 2 cols
  int b = t >> 1, jj = t & 1;
  float acc = bias[jj];
  for (int r = 0; r < 128; ++r) {
    float v = fmaxf(fmaf(t2raw[b * 128 + r], sc[r], sh[r]), 0.f);
    acc = fmaf(v, W[r * 2 + jj], acc);
  }
  out[t] = acc;
}

// ---------------------------------------------------------------- per-layer driver

struct LayerPtrs {
  int* idx; float *p, *q, *zmx, *zmn, *stats;
  u16 *Wh, *Wl;
};

template<int C>
static void run_edgeconv(const float* xin, int Cin,
                         const float* W1, const float* b1, const float* g1, const float* e1,
                         const float* W2, const float* b2, const float* g2, const float* e2,
                         float* hout, const LayerPtrs& L, hipStream_t stream) {
  float* s1 = L.stats;
  float* ss1 = L.stats + 256;
  float* s2 = L.stats + 512;
  float* ss2 = L.stats + 768;
  float* sc1 = L.stats + 1024;
  float* sh1 = L.stats + 1280;
  float* sc2 = L.stats + 1536;
  float* sh2 = L.stats + 1792;

  (void)hipMemsetAsync(L.stats, 0, 4 * 256 * sizeof(float), stream);
  knn_kernel<<<dim3(MNODE), dim3(64), 0, stream>>>(xin, Cin, L.idx);
  node_gemm<<<dim3(MNODE / 8), dim3(C), 0, stream>>>(xin, W1, L.p, L.q, Cin, C);
  pack_w2<C><<<dim3((C * C + 255) / 256), dim3(256), 0, stream>>>(W2, L.Wh, L.Wl);
  edge_stats1v<C><<<dim3(MNODE / 4), dim3(256), 0, stream>>>(L.p, L.q, b1, L.idx, s1, ss1);
  bn_params<<<dim3(1), dim3(C), 0, stream>>>(s1, ss1, g1, e1, b1, (float)MEDGE, sc1, sh1);
  edge_gemm2_mfma16<C><<<dim3(MNODE / 4), dim3(256), 0, stream>>>(
      L.p, L.q, L.idx, sc1, sh1, L.Wh, L.Wl, b2, L.zmx, L.zmn, s2, ss2);
  bn_params<<<dim3(1), dim3(C), 0, stream>>>(s2, ss2, g2, e2, nullptr, (float)MEDGE, sc2, sh2);
  finalize_kernel<<<dim3(MNODE * C / 256), dim3(256), 0, stream>>>(L.zmx, L.zmn, sc2, sh2,
                                                                   hout, C - 1);
}

// ---------------------------------------------------------------- launch

extern "C" void kernel_launch(void* const* d_in, const int* in_sizes, int n_in,
                              void* d_out, int out_size, void* d_ws, size_t ws_size,
                              hipStream_t stream) {
  const float* x   = (const float*)d_in[0];
  const float* w11 = (const float*)d_in[1];
  const float* b11 = (const float*)d_in[2];
  const float* g11 = (const float*)d_in[3];
  const float* e11 = (const float*)d_in[4];
  const float* w12 = (const float*)d_in[5];
  const float* b12 = (const float*)d_in[6];
  const float* g12 = (const float*)d_in[7];
  const float* e12 = (const float*)d_in[8];
  const float* w21 = (const float*)d_in[9];
  const float* b21 = (const float*)d_in[10];
  const float* g21 = (const float*)d_in[11];
  const float* e21 = (const float*)d_in[12];
  const float* w22 = (const float*)d_in[13];
  const float* b22 = (const float*)d_in[14];
  const float* g22 = (const float*)d_in[15];
  const float* e22 = (const float*)d_in[16];
  const float* w31 = (const float*)d_in[17];
  const float* b31 = (const float*)d_in[18];
  const float* g31 = (const float*)d_in[19];
  const float* e31 = (const float*)d_in[20];
  const float* w32 = (const float*)d_in[21];
  const float* b32 = (const float*)d_in[22];
  const float* g32 = (const float*)d_in[23];
  const float* e32 = (const float*)d_in[24];
  const float* fw1 = (const float*)d_in[25];
  const float* fb1 = (const float*)d_in[26];
  const float* fg1 = (const float*)d_in[27];
  const float* fe1 = (const float*)d_in[28];
  const float* fw2 = (const float*)d_in[29];
  const float* fb2 = (const float*)d_in[30];
  const float* fg2 = (const float*)d_in[31];
  const float* fe2 = (const float*)d_in[32];
  const float* fw3 = (const float*)d_in[33];
  const float* fb3 = (const float*)d_in[34];

  char* wsb = (char*)d_ws;
  size_t o = 0;
  auto alloc = [&](size_t bytes) -> void* {
    void* r = wsb + o;
    o += (bytes + 255) & ~(size_t)255;
    return r;
  };
  LayerPtrs L;
  L.idx   = (int*)  alloc((size_t)MNODE * KK * sizeof(int));
  L.p     = (float*)alloc((size_t)MNODE * 256 * sizeof(float));
  L.q     = (float*)alloc((size_t)MNODE * 256 * sizeof(float));
  L.zmx   = (float*)alloc((size_t)MNODE * 256 * sizeof(float));
  L.zmn   = (float*)alloc((size_t)MNODE * 256 * sizeof(float));
  L.stats = (float*)alloc(8 * 256 * sizeof(float));
  L.Wh    = (u16*)  alloc((size_t)256 * 256 * sizeof(u16));
  L.Wl    = (u16*)  alloc((size_t)256 * 256 * sizeof(u16));
  float* h1buf   = (float*)alloc((size_t)MNODE * 64 * sizeof(float));
  float* h2buf   = (float*)alloc((size_t)MNODE * 128 * sizeof(float));
  float* h3buf   = (float*)alloc((size_t)MNODE * 256 * sizeof(float));
  float* pooled  = (float*)alloc(128 * 512 * sizeof(float));
  float* t1raw   = (float*)alloc(128 * 256 * sizeof(float));
  float* t2raw   = (float*)alloc(128 * 128 * sizeof(float));
  float* fcstats = (float*)alloc(8 * 256 * sizeof(float));

  float* fs  = fcstats;
  float* fss = fcstats + 256;
  float* fsc = fcstats + 512;
  float* fsh = fcstats + 768;
  float* gs  = fcstats + 1024;
  float* gss = fcstats + 1280;
  float* gsc = fcstats + 1536;
  float* gsh = fcstats + 1792;

  (void)hipMemsetAsync(fcstats, 0, 8 * 256 * sizeof(float), stream);

  run_edgeconv<64 >(x,     6,   w11, b11, g11, e11, w12, b12, g12, e12, h1buf, L, stream);
  run_edgeconv<128>(h1buf, 64,  w21, b21, g21, e21, w22, b22, g22, e22, h2buf, L, stream);
  run_edgeconv<256>(h2buf, 128, w31, b31, g31, e31, w32, b32, g32, e32, h3buf, L, stream);

  pool_kernel<<<dim3(BB), dim3(256), 0, stream>>>(h3buf, pooled);
  fc1_fused<<<dim3(BB), dim3(256), 0, stream>>>(pooled, fw1, fb1, t1raw, fs, fss);
  bn_params<<<dim3(1), dim3(256), 0, stream>>>(fs, fss, fg1, fe1, nullptr, 128.f, fsc, fsh);
  fc2_fused<<<dim3(BB), dim3(256), 0, stream>>>(t1raw, fsc, fsh, fw2, fb2, t2raw, gs, gss);
  bn_params<<<dim3(1), dim3(128), 0, stream>>>(gs, gss, fg2, fe2, nullptr, 128.f, gsc, gsh);
  fc3_fused<<<dim3(1), dim3(256), 0, stream>>>(t2raw, gsc, gsh, fw3, fb3, (float*)d_out);
}

// Round 6
// 1175.289 us; speedup vs baseline: 1.9680x; 1.3082x over previous
//
#include <hip/hip_runtime.h>
#include <math.h>

#define BB 128
#define NN 128
#define KK 16
#define MEDGE (BB*NN*KK)   // 262144 edges
#define MNODE (BB*NN)      // 16384 nodes

typedef __bf16 bf16x8 __attribute__((ext_vector_type(8)));
typedef float  floatx16 __attribute__((ext_vector_type(16)));
typedef unsigned short u16;
typedef u16 ushort8_alias __attribute__((ext_vector_type(8)));

// ---------------------------------------------------------------- utilities

__device__ __forceinline__ unsigned ord32(float f) {
  unsigned u = __float_as_uint(f);
  return (u & 0x80000000u) ? ~u : (u | 0x80000000u);
}

__device__ __forceinline__ unsigned long long shfl_xor_u64(unsigned long long v, int m) {
  unsigned lo = (unsigned)(v & 0xffffffffull);
  unsigned hi = (unsigned)(v >> 32);
  lo = __shfl_xor(lo, m, 64);
  hi = __shfl_xor(hi, m, 64);
  return (((unsigned long long)hi) << 32) | (unsigned long long)lo;
}

// ---------------------------------------------------------------- kNN: distances
// One block per (batch, row-quarter). x chunked by <=64 channels into LDS
// (coalesced fill), 4x4 register-tiled dot products, fma order identical to
// the reference-passing version (sequential over c). D[node][m] fp32.
template<int C>
__global__ __launch_bounds__(256) void dist_kernel(const float* __restrict__ x,
                                                   float* __restrict__ D) {
  constexpr int CH = (C < 64) ? C : 64;   // channels per pass
  constexpr int NP = C / CH;              // passes
  constexpr int S = CH + 2;
  __shared__ float xs[NN * S];
  __shared__ float sq[NN];
  int b = blockIdx.x >> 2, qr = blockIdx.x & 3;
  const float* xb = x + (size_t)b * NN * C;
  int rg = threadIdx.x >> 5, cg = threadIdx.x & 31;
  int r0 = qr * 32 + rg * 4;

  float acc[4][4];
#pragma unroll
  for (int i = 0; i < 4; ++i)
#pragma unroll
    for (int j = 0; j < 4; ++j) acc[i][j] = 0.f;
  float sqacc = 0.f;

  for (int ps = 0; ps < NP; ++ps) {
    int c0 = ps * CH;
    __syncthreads();
    for (int t = threadIdx.x; t < NN * CH; t += 256) {
      int row = t / CH, c = t - row * CH;
      xs[row * S + c] = xb[(size_t)row * C + c0 + c];
    }
    __syncthreads();
    if (threadIdx.x < NN) {
      const float* xr = xs + threadIdx.x * S;
      float s = sqacc;
      for (int c = 0; c < CH; ++c) s = fmaf(xr[c], xr[c], s);
      sqacc = s;
    }
    for (int c = 0; c < CH; c += 2) {
      float2 av[4], bv[4];
#pragma unroll
      for (int i = 0; i < 4; ++i) av[i] = *(const float2*)&xs[(r0 + i) * S + c];
#pragma unroll
      for (int j = 0; j < 4; ++j) bv[j] = *(const float2*)&xs[(cg + 32 * j) * S + c];
#pragma unroll
      for (int i = 0; i < 4; ++i)
#pragma unroll
        for (int j = 0; j < 4; ++j) {
          acc[i][j] = fmaf(av[i].x, bv[j].x, acc[i][j]);
          acc[i][j] = fmaf(av[i].y, bv[j].y, acc[i][j]);
        }
    }
  }
  __syncthreads();
  if (threadIdx.x < NN) sq[threadIdx.x] = sqacc;
  __syncthreads();
#pragma unroll
  for (int i = 0; i < 4; ++i) {
    float sn = sq[r0 + i];
#pragma unroll
    for (int j = 0; j < 4; ++j) {
      int m = cg + 32 * j;
      D[((size_t)(b * NN + r0 + i)) * NN + m] = sn - 2.f * acc[i][j] + sq[m];
    }
  }
}

// ---------------------------------------------------------------- kNN: selection
// One wave per node; 16 rounds of packed (dist,idx) u64 wave-min (ties -> lower idx).
__global__ __launch_bounds__(256) void select_kernel(const float* __restrict__ D,
                                                     int* __restrict__ idx) {
  int lane = threadIdx.x & 63, wv = threadIdx.x >> 6;
  int nd = blockIdx.x * 4 + wv;
  const float* dr = D + (size_t)nd * NN;
  unsigned long long key[2];
  key[0] = (((unsigned long long)ord32(dr[lane])) << 32) | (unsigned)lane;
  key[1] = (((unsigned long long)ord32(dr[lane + 64])) << 32) | (unsigned)(lane + 64);
  int* out = idx + (size_t)nd * KK;
  for (int r = 0; r < KK; ++r) {
    unsigned long long mk = key[0] < key[1] ? key[0] : key[1];
#pragma unroll
    for (int off = 32; off > 0; off >>= 1) {
      unsigned long long o = shfl_xor_u64(mk, off);
      if (o < mk) mk = o;
    }
    int wm = (int)(mk & 0xffffffffu);
    if (lane == 0) out[r] = wm;
    if ((wm & 63) == lane) key[wm >> 6] = ~0ull;
  }
}

// ---------------------------------------------------------------- node GEMM
// p = x @ (W1_top - W1_bot),  q = x @ W1_bot    (W1 is [2*Cin, Cout] row-major)
__global__ __launch_bounds__(256) void node_gemm(const float* __restrict__ x,
                                                 const float* __restrict__ W,
                                                 float* __restrict__ p, float* __restrict__ q,
                                                 int Cin, int Cout) {
  int c = threadIdx.x;
  __shared__ float xr[128];
  for (int r = 0; r < 8; ++r) {
    int row = blockIdx.x * 8 + r;
    __syncthreads();
    for (int i = c; i < Cin; i += blockDim.x) xr[i] = x[(size_t)row * Cin + i];
    __syncthreads();
    float a = 0.f, qv = 0.f;
    for (int i = 0; i < Cin; ++i) {
      float xv = xr[i];
      a  = fmaf(xv, W[i * Cout + c], a);
      qv = fmaf(xv, W[(Cin + i) * Cout + c], qv);
    }
    p[(size_t)row * Cout + c] = a - qv;
    q[(size_t)row * Cout + c] = qv;
  }
}

// ---------------------------------------------------------------- BN1 stats (vectorized)
template<int C>
__global__ __launch_bounds__(256) void edge_stats1v(const float* __restrict__ p,
                                                    const float* __restrict__ q,
                                                    const float* __restrict__ b1,
                                                    const int* __restrict__ idx,
                                                    float* __restrict__ s1,
                                                    float* __restrict__ ss1) {
  constexpr int G = C / 4;
  constexpr int KL = 64 / G;
  int tid = threadIdx.x, lane = tid & 63, wv = tid >> 6;
  int nd = blockIdx.x * 4 + wv;
  int b = nd >> 7;
  int g = lane % G, kl = lane / G;

  __shared__ float sS[C], sSS[C];
  if (tid < C) { sS[tid] = 0.f; sSS[tid] = 0.f; }
  __syncthreads();

  const float* pr = p + (size_t)nd * C;
  float4 pv = *(const float4*)(pr + g * 4);
  float4 bv = *(const float4*)(b1 + g * 4);
  pv.x += bv.x; pv.y += bv.y; pv.z += bv.z; pv.w += bv.w;
  float4 s = {0, 0, 0, 0}, ss = {0, 0, 0, 0};
  const int* id = idx + (size_t)nd * KK;
#pragma unroll
  for (int k0 = 0; k0 < KK; k0 += KL) {
    int j = id[k0 + kl];
    float4 q4 = *(const float4*)(q + (size_t)(b * NN + j) * C + g * 4);
    float y;
    y = pv.x + q4.x; s.x += y; ss.x = fmaf(y, y, ss.x);
    y = pv.y + q4.y; s.y += y; ss.y = fmaf(y, y, ss.y);
    y = pv.z + q4.z; s.z += y; ss.z = fmaf(y, y, ss.z);
    y = pv.w + q4.w; s.w += y; ss.w = fmaf(y, y, ss.w);
  }
#pragma unroll
  for (int off = G; off < 64; off <<= 1) {
    s.x += __shfl_xor(s.x, off); ss.x += __shfl_xor(ss.x, off);
    s.y += __shfl_xor(s.y, off); ss.y += __shfl_xor(ss.y, off);
    s.z += __shfl_xor(s.z, off); ss.z += __shfl_xor(ss.z, off);
    s.w += __shfl_xor(s.w, off); ss.w += __shfl_xor(ss.w, off);
  }
  if (kl == 0) {
    atomicAdd(&sS[g * 4 + 0], s.x); atomicAdd(&sSS[g * 4 + 0], ss.x);
    atomicAdd(&sS[g * 4 + 1], s.y); atomicAdd(&sSS[g * 4 + 1], ss.y);
    atomicAdd(&sS[g * 4 + 2], s.z); atomicAdd(&sSS[g * 4 + 2], ss.z);
    atomicAdd(&sS[g * 4 + 3], s.w); atomicAdd(&sSS[g * 4 + 3], ss.w);
  }
  __syncthreads();
  if (tid < C) {
    atomicAdd(&s1[tid], sS[tid]);
    atomicAdd(&ss1[tid], sSS[tid]);
  }
}

// ---------------------------------------------------------------- BN params
__global__ void bn_params(const float* __restrict__ s, const float* __restrict__ ss,
                          const float* __restrict__ g, const float* __restrict__ beta,
                          const float* __restrict__ bias,
                          float M, float* __restrict__ scale, float* __restrict__ shift) {
  int c = threadIdx.x;
  float mean = s[c] / M;
  float var = ss[c] / M - mean * mean;
  if (var < 0.f) var = 0.f;
  float sc = g[c] * rsqrtf(var + 1e-5f);
  scale[c] = sc;
  float sh = beta[c] - mean * sc;
  if (bias) sh += sc * bias[c];
  shift[c] = sh;
}

// ---------------------------------------------------------------- W2 packing (32x32x16)
// B operand of v_mfma_f32_32x32x16_bf16: B[k][n], n = lane&31, k = (lane>>5)*8+j.
// Flat ushort8 chunk index: (kt*NT + nt)*64 + lane.
__device__ __forceinline__ u16 bf16_rne_bits(float x) {
  unsigned u = __float_as_uint(x);
  return (u16)((u + 0x7FFF + ((u >> 16) & 1)) >> 16);
}

template<int C>
__global__ __launch_bounds__(256) void pack_w2(const float* __restrict__ W,
                                               u16* __restrict__ Wh, u16* __restrict__ Wl) {
  int t = blockIdx.x * 256 + threadIdx.x;
  if (t >= C * C) return;
  constexpr int NT = C / 32;
  int j = t & 7, lane = (t >> 3) & 63, ktnt = t >> 9;
  int nt = ktnt % NT, kt = ktnt / NT;
  int row = kt * 16 + (lane >> 5) * 8 + j;
  int col = nt * 32 + (lane & 31);
  float w = W[row * C + col];
  u16 h = bf16_rne_bits(w);
  float hf = __uint_as_float(((unsigned)h) << 16);
  Wh[t] = h;
  Wl[t] = bf16_rne_bits(w - hf);
}

// ---------------------------------------------------------------- MFMA edge GEMM2 v3
// Block = 4 waves = 8 nodes. Wave = 2 M-tiles (4 nodes) x N-half.
// B (hi+lo) staged per k-tile into double-buffered LDS, shared by all waves:
// W2 read from L2 ONCE per block. 3 MFMAs per (mt,nt): Ah*Bh + Al*Bh + Ah*Bl.
// Epilogue: per-node max/min over k + BN2 sum/sumsq from acc regs, LDS-reduced.
template<int C>
__global__ __launch_bounds__(256, 2) void edge_gemm2_v3(
    const float* __restrict__ p, const float* __restrict__ q,
    const int* __restrict__ idx,
    const float* __restrict__ sc1, const float* __restrict__ sh1,  // bias1 folded into sh1
    const u16* __restrict__ Wh, const u16* __restrict__ Wl,
    const float* __restrict__ b2,
    float* __restrict__ zmax, float* __restrict__ zmin,
    float* __restrict__ s2, float* __restrict__ ss2) {
  constexpr int KT = C / 16, NT = C / 32, NTH = NT / 2;
  constexpr int CHK = NT * 64;  // ushort8 chunks per array per k-tile
  __shared__ __align__(16) u16 Bst[2][2][CHK * 8];
  __shared__ float sS[C], sSS[C];
  int tid = threadIdx.x, lane = tid & 63, wv = tid >> 6;
  int m = lane & 31, lh = lane >> 5;
  int mpair = wv >> 1, nhalf = wv & 1;

  if (tid < C) { sS[tid] = 0.f; sSS[tid] = 0.f; }

  // XCD swizzle: 2048 blocks, 8 nodes/block, 16 blocks/batch share an XCD.
  int u = blockIdx.x >> 3, xcd = blockIdx.x & 7;
  int b = xcd + 8 * (u >> 4);
  int nodeBase = b * NN + (u & 15) * 8;
  int wBase = nodeBase + mpair * 4;

  const float *pr[2], *qr[2];
#pragma unroll
  for (int mt = 0; mt < 2; ++mt) {
    int nd = wBase + mt * 2 + (m >> 4);
    int j = idx[(size_t)nd * KK + (m & 15)];
    pr[mt] = p + (size_t)nd * C;
    qr[mt] = q + (size_t)(b * NN + j) * C;
  }

  floatx16 acc[2][NTH];
#pragma unroll
  for (int mt = 0; mt < 2; ++mt)
#pragma unroll
    for (int nt = 0; nt < NTH; ++nt) {
      float bv = b2[(nhalf * NTH + nt) * 32 + m];
#pragma unroll
      for (int r = 0; r < 16; ++r) acc[mt][nt][r] = bv;
    }

  auto stage = [&](int kt, int buf) {
    const ushort8_alias* srcH = (const ushort8_alias*)Wh + (size_t)kt * CHK;
    const ushort8_alias* srcL = (const ushort8_alias*)Wl + (size_t)kt * CHK;
    ushort8_alias* dH = (ushort8_alias*)Bst[buf][0];
    ushort8_alias* dL = (ushort8_alias*)Bst[buf][1];
    for (int i = tid; i < CHK; i += 256) { dH[i] = srcH[i]; dL[i] = srcL[i]; }
  };
  stage(0, 0);
  __syncthreads();

  for (int kt = 0; kt < KT; ++kt) {
    int buf = kt & 1;
    if (kt + 1 < KT) stage(kt + 1, buf ^ 1);

    // build A fragments for this k-tile (hi + lo bf16 split)
    int c0 = kt * 16 + lh * 8;
    float4 sa = *(const float4*)(sc1 + c0);
    float4 sb = *(const float4*)(sc1 + c0 + 4);
    float4 ta = *(const float4*)(sh1 + c0);
    float4 tb = *(const float4*)(sh1 + c0 + 4);
    bf16x8 ah[2], al[2];
#pragma unroll
    for (int mt = 0; mt < 2; ++mt) {
      float4 pa = *(const float4*)(pr[mt] + c0);
      float4 pb = *(const float4*)(pr[mt] + c0 + 4);
      float4 qa = *(const float4*)(qr[mt] + c0);
      float4 qb = *(const float4*)(qr[mt] + c0 + 4);
      float hv[8];
      hv[0] = fmaxf(fmaf(pa.x + qa.x, sa.x, ta.x), 0.f);
      hv[1] = fmaxf(fmaf(pa.y + qa.y, sa.y, ta.y), 0.f);
      hv[2] = fmaxf(fmaf(pa.z + qa.z, sa.z, ta.z), 0.f);
      hv[3] = fmaxf(fmaf(pa.w + qa.w, sa.w, ta.w), 0.f);
      hv[4] = fmaxf(fmaf(pb.x + qb.x, sb.x, tb.x), 0.f);
      hv[5] = fmaxf(fmaf(pb.y + qb.y, sb.y, tb.y), 0.f);
      hv[6] = fmaxf(fmaf(pb.z + qb.z, sb.z, tb.z), 0.f);
      hv[7] = fmaxf(fmaf(pb.w + qb.w, sb.w, tb.w), 0.f);
#pragma unroll
      for (int t = 0; t < 8; ++t) {
        __bf16 hb = (__bf16)hv[t];
        ah[mt][t] = hb;
        al[mt][t] = (__bf16)(hv[t] - (float)hb);
      }
    }

#pragma unroll
    for (int nt = 0; nt < NTH; ++nt) {
      int e = (nhalf * NTH + nt) * 64 + lane;
      bf16x8 bh = __builtin_bit_cast(bf16x8, ((const ushort8_alias*)Bst[buf][0])[e]);
      bf16x8 bl = __builtin_bit_cast(bf16x8, ((const ushort8_alias*)Bst[buf][1])[e]);
#pragma unroll
      for (int mt = 0; mt < 2; ++mt) {
        acc[mt][nt] = __builtin_amdgcn_mfma_f32_32x32x16_bf16(ah[mt], bh, acc[mt][nt], 0, 0, 0);
        acc[mt][nt] = __builtin_amdgcn_mfma_f32_32x32x16_bf16(al[mt], bh, acc[mt][nt], 0, 0, 0);
        acc[mt][nt] = __builtin_amdgcn_mfma_f32_32x32x16_bf16(ah[mt], bl, acc[mt][nt], 0, 0, 0);
      }
    }
    __syncthreads();
  }

  // epilogue: acc row = (r&3)+8*(r>>2)+4*lh; regs 0..7 -> first node's 16 k,
  // regs 8..15 -> second node. col = (nhalf*NTH+nt)*32 + m.
#pragma unroll
  for (int mt = 0; mt < 2; ++mt)
#pragma unroll
    for (int nt = 0; nt < NTH; ++nt) {
      float s = 0.f, ss = 0.f;
      float mxA = -INFINITY, mnA = INFINITY, mxB = -INFINITY, mnB = INFINITY;
#pragma unroll
      for (int r = 0; r < 8; ++r) {
        float z = acc[mt][nt][r];
        s += z; ss = fmaf(z, z, ss);
        mxA = fmaxf(mxA, z); mnA = fminf(mnA, z);
      }
#pragma unroll
      for (int r = 8; r < 16; ++r) {
        float z = acc[mt][nt][r];
        s += z; ss = fmaf(z, z, ss);
        mxB = fmaxf(mxB, z); mnB = fminf(mnB, z);
      }
      mxA = fmaxf(mxA, __shfl_xor(mxA, 32)); mnA = fminf(mnA, __shfl_xor(mnA, 32));
      mxB = fmaxf(mxB, __shfl_xor(mxB, 32)); mnB = fminf(mnB, __shfl_xor(mnB, 32));
      float sw = s + __shfl_xor(s, 32);
      float ssw = ss + __shfl_xor(ss, 32);
      if (lane < 32) {
        int col = (nhalf * NTH + nt) * 32 + m;
        int ndA = wBase + mt * 2;
        zmax[(size_t)ndA * C + col] = mxA;
        zmin[(size_t)ndA * C + col] = mnA;
        zmax[(size_t)(ndA + 1) * C + col] = mxB;
        zmin[(size_t)(ndA + 1) * C + col] = mnB;
        atomicAdd(&sS[col], sw);
        atomicAdd(&sSS[col], ssw);
      }
    }
  __syncthreads();
  if (tid < C) {
    atomicAdd(&s2[tid], sS[tid]);
    atomicAdd(&ss2[tid], sSS[tid]);
  }
}

// ---------------------------------------------------------------- finalize
__global__ __launch_bounds__(256) void finalize_kernel(const float* __restrict__ zmax,
                                                       const float* __restrict__ zmin,
                                                       const float* __restrict__ sc2,
                                                       const float* __restrict__ sh2,
                                                       float* __restrict__ out, int Cmask) {
  int t = blockIdx.x * 256 + threadIdx.x;
  int c = t & Cmask;
  float scl = sc2[c];
  float v = (scl >= 0.f) ? zmax[t] : zmin[t];
  out[t] = fmaxf(fmaf(v, scl, sh2[c]), 0.f);
}

// ---------------------------------------------------------------- pooling
__global__ __launch_bounds__(256) void pool_kernel(const float* __restrict__ h,
                                                   float* __restrict__ pooled) {
  int b = blockIdx.x, c = threadIdx.x;
  float s = 0.f, mx = -INFINITY;
  for (int n = 0; n < NN; ++n) {
    float v = h[(size_t)(b * NN + n) * 256 + c];
    s += v;
    mx = fmaxf(mx, v);
  }
  pooled[b * 512 + c] = s * (1.f / 128.f);
  pooled[b * 512 + 256 + c] = mx;
}

// ---------------------------------------------------------------- FC tail
__global__ __launch_bounds__(256) void fc1_fused(const float* __restrict__ pooled,
                                                 const float* __restrict__ W,
                                                 const float* __restrict__ bias,
                                                 float* __restrict__ t1raw,
                                                 float* __restrict__ fs, float* __restrict__ fss) {
  int b = blockIdx.x, c = threadIdx.x;
  __shared__ float row[512];
  row[c] = pooled[b * 512 + c];
  row[c + 256] = pooled[b * 512 + 256 + c];
  __syncthreads();
  float acc = bias[c];
  for (int i = 0; i < 512; ++i) acc = fmaf(row[i], W[i * 256 + c], acc);
  t1raw[b * 256 + c] = acc;
  atomicAdd(&fs[c], acc);
  atomicAdd(&fss[c], acc * acc);
}

__global__ __launch_bounds__(256) void fc2_fused(const float* __restrict__ t1raw,
                                                 const float* __restrict__ sc,
                                                 const float* __restrict__ sh,
                                                 const float* __restrict__ W,
                                                 const float* __restrict__ bias,
                                                 float* __restrict__ t2raw,
                                                 float* __restrict__ gs, float* __restrict__ gss) {
  int b = blockIdx.x, c = threadIdx.x;
  __shared__ float row[256];
  row[c] = fmaxf(fmaf(t1raw[b * 256 + c], sc[c], sh[c]), 0.f);
  __syncthreads();
  if (c < 128) {
    float acc = bias[c];
    for (int i = 0; i < 256; ++i) acc = fmaf(row[i], W[i * 128 + c], acc);
    t2raw[b * 128 + c] = acc;
    atomicAdd(&gs[c], acc);
    atomicAdd(&gss[c], acc * acc);
  }
}

__global__ __launch_bounds__(256) void fc3_fused(const float* __restrict__ t2raw,
                                                 const float* __restrict__ sc,
                                                 const float* __restrict__ sh,
                                                 const float* __restrict__ W,
                                                 const float* __restrict__ bias,
                                                 float* __restrict__ out) {
  int t = threadIdx.x;
  int b = t >> 1, jj = t & 1;
  float acc = bias[jj];
  for (int r = 0; r < 128; ++r) {
    float v = fmaxf(fmaf(t2raw[b * 128 + r], sc[r], sh[r]), 0.f);
    acc = fmaf(v, W[r * 2 + jj], acc);
  }
  out[t] = acc;
}

// ---------------------------------------------------------------- per-layer driver

struct LayerPtrs {
  int* idx; float *p, *q, *zmx, *zmn, *stats, *D;
  u16 *Wh, *Wl;
};

template<int Cin, int C>
static void run_edgeconv(const float* xin,
                         const float* W1, const float* b1, const float* g1, const float* e1,
                         const float* W2, const float* b2, const float* g2, const float* e2,
                         float* hout, const LayerPtrs& L, hipStream_t stream) {
  float* s1 = L.stats;
  float* ss1 = L.stats + 256;
  float* s2 = L.stats + 512;
  float* ss2 = L.stats + 768;
  float* sc1 = L.stats + 1024;
  float* sh1 = L.stats + 1280;
  float* sc2 = L.stats + 1536;
  float* sh2 = L.stats + 1792;

  (void)hipMemsetAsync(L.stats, 0, 4 * 256 * sizeof(float), stream);
  dist_kernel<Cin><<<dim3(BB * 4), dim3(256), 0, stream>>>(xin, L.D);
  select_kernel<<<dim3(MNODE / 4), dim3(256), 0, stream>>>(L.D, L.idx);
  node_gemm<<<dim3(MNODE / 8), dim3(C), 0, stream>>>(xin, W1, L.p, L.q, Cin, C);
  pack_w2<C><<<dim3((C * C + 255) / 256), dim3(256), 0, stream>>>(W2, L.Wh, L.Wl);
  edge_stats1v<C><<<dim3(MNODE / 4), dim3(256), 0, stream>>>(L.p, L.q, b1, L.idx, s1, ss1);
  bn_params<<<dim3(1), dim3(C), 0, stream>>>(s1, ss1, g1, e1, b1, (float)MEDGE, sc1, sh1);
  edge_gemm2_v3<C><<<dim3(MNODE / 8), dim3(256), 0, stream>>>(
      L.p, L.q, L.idx, sc1, sh1, L.Wh, L.Wl, b2, L.zmx, L.zmn, s2, ss2);
  bn_params<<<dim3(1), dim3(C), 0, stream>>>(s2, ss2, g2, e2, nullptr, (float)MEDGE, sc2, sh2);
  finalize_kernel<<<dim3(MNODE * C / 256), dim3(256), 0, stream>>>(L.zmx, L.zmn, sc2, sh2,
                                                                   hout, C - 1);
}

// ---------------------------------------------------------------- launch

extern "C" void kernel_launch(void* const* d_in, const int* in_sizes, int n_in,
                              void* d_out, int out_size, void* d_ws, size_t ws_size,
                              hipStream_t stream) {
  const float* x   = (const float*)d_in[0];
  const float* w11 = (const float*)d_in[1];
  const float* b11 = (const float*)d_in[2];
  const float* g11 = (const float*)d_in[3];
  const float* e11 = (const float*)d_in[4];
  const float* w12 = (const float*)d_in[5];
  const float* b12 = (const float*)d_in[6];
  const float* g12 = (const float*)d_in[7];
  const float* e12 = (const float*)d_in[8];
  const float* w21 = (const float*)d_in[9];
  const float* b21 = (const float*)d_in[10];
  const float* g21 = (const float*)d_in[11];
  const float* e21 = (const float*)d_in[12];
  const float* w22 = (const float*)d_in[13];
  const float* b22 = (const float*)d_in[14];
  const float* g22 = (const float*)d_in[15];
  const float* e22 = (const float*)d_in[16];
  const float* w31 = (const float*)d_in[17];
  const float* b31 = (const float*)d_in[18];
  const float* g31 = (const float*)d_in[19];
  const float* e31 = (const float*)d_in[20];
  const float* w32 = (const float*)d_in[21];
  const float* b32 = (const float*)d_in[22];
  const float* g32 = (const float*)d_in[23];
  const float* e32 = (const float*)d_in[24];
  const float* fw1 = (const float*)d_in[25];
  const float* fb1 = (const float*)d_in[26];
  const float* fg1 = (const float*)d_in[27];
  const float* fe1 = (const float*)d_in[28];
  const float* fw2 = (const float*)d_in[29];
  const float* fb2 = (const float*)d_in[30];
  const float* fg2 = (const float*)d_in[31];
  const float* fe2 = (const float*)d_in[32];
  const float* fw3 = (const float*)d_in[33];
  const float* fb3 = (const float*)d_in[34];

  char* wsb = (char*)d_ws;
  size_t o = 0;
  auto alloc = [&](size_t bytes) -> void* {
    void* r = wsb + o;
    o += (bytes + 255) & ~(size_t)255;
    return r;
  };
  LayerPtrs L;
  L.idx   = (int*)  alloc((size_t)MNODE * KK * sizeof(int));
  L.p     = (float*)alloc((size_t)MNODE * 256 * sizeof(float));
  L.q     = (float*)alloc((size_t)MNODE * 256 * sizeof(float));
  L.zmx   = (float*)alloc((size_t)MNODE * 256 * sizeof(float));
  L.zmn   = (float*)alloc((size_t)MNODE * 256 * sizeof(float));
  L.stats = (float*)alloc(8 * 256 * sizeof(float));
  L.D     = (float*)alloc((size_t)MNODE * NN * sizeof(float));
  L.Wh    = (u16*)  alloc((size_t)256 * 256 * sizeof(u16));
  L.Wl    = (u16*)  alloc((size_t)256 * 256 * sizeof(u16));
  float* h1buf   = (float*)alloc((size_t)MNODE * 64 * sizeof(float));
  float* h2buf   = (float*)alloc((size_t)MNODE * 128 * sizeof(float));
  float* h3buf   = (float*)alloc((size_t)MNODE * 256 * sizeof(float));
  float* pooled  = (float*)alloc(128 * 512 * sizeof(float));
  float* t1raw   = (float*)alloc(128 * 256 * sizeof(float));
  float* t2raw   = (float*)alloc(128 * 128 * sizeof(float));
  float* fcstats = (float*)alloc(8 * 256 * sizeof(float));

  float* fs  = fcstats;
  float* fss = fcstats + 256;
  float* fsc = fcstats + 512;
  float* fsh = fcstats + 768;
  float* gs  = fcstats + 1024;
  float* gss = fcstats + 1280;
  float* gsc = fcstats + 1536;
  float* gsh = fcstats + 1792;

  (void)hipMemsetAsync(fcstats, 0, 8 * 256 * sizeof(float), stream);

  run_edgeconv<6,   64 >(x,     w11, b11, g11, e11, w12, b12, g12, e12, h1buf, L, stream);
  run_edgeconv<64,  128>(h1buf, w21, b21, g21, e21, w22, b22, g22, e22, h2buf, L, stream);
  run_edgeconv<128, 256>(h2buf, w31, b31, g31, e31, w32, b32, g32, e32, h3buf, L, stream);

  pool_kernel<<<dim3(BB), dim3(256), 0, stream>>>(h3buf, pooled);
  fc1_fused<<<dim3(BB), dim3(256), 0, stream>>>(pooled, fw1, fb1, t1raw, fs, fss);
  bn_params<<<dim3(1), dim3(256), 0, stream>>>(fs, fss, fg1, fe1, nullptr, 128.f, fsc, fsh);
  fc2_fused<<<dim3(BB), dim3(256), 0, stream>>>(t1raw, fsc, fsh, fw2, fb2, t2raw, gs, gss);
  bn_params<<<dim3(1), dim3(128), 0, stream>>>(gs, gss, fg2, fe2, nullptr, 128.f, gsc, gsh);
  fc3_fused<<<dim3(1), dim3(256), 0, stream>>>(t2raw, gsc, gsh, fw3, fb3, (float*)d_out);
}

// Round 7
// 1029.554 us; speedup vs baseline: 2.2466x; 1.1416x over previous
//
#include <hip/hip_runtime.h>
#include <math.h>

#define BB 128
#define NN 128
#define KK 16
#define MEDGE (BB*NN*KK)   // 262144 edges
#define MNODE (BB*NN)      // 16384 nodes

typedef __bf16 bf16x8 __attribute__((ext_vector_type(8)));
typedef float  floatx16 __attribute__((ext_vector_type(16)));
typedef unsigned short u16;
typedef u16 ushort8_alias __attribute__((ext_vector_type(8)));

// ---------------------------------------------------------------- utilities

__device__ __forceinline__ unsigned ord32(float f) {
  unsigned u = __float_as_uint(f);
  return (u & 0x80000000u) ? ~u : (u | 0x80000000u);
}

__device__ __forceinline__ unsigned long long shfl_xor_u64(unsigned long long v, int m) {
  unsigned lo = (unsigned)(v & 0xffffffffull);
  unsigned hi = (unsigned)(v >> 32);
  lo = __shfl_xor(lo, m, 64);
  hi = __shfl_xor(hi, m, 64);
  return (((unsigned long long)hi) << 32) | (unsigned long long)lo;
}

__device__ __forceinline__ u16 bf16_rne_bits(float x) {
  unsigned u = __float_as_uint(x);
  return (u16)((u + 0x7FFF + ((u >> 16) & 1)) >> 16);
}

// ---------------------------------------------------------------- kNN: distances
template<int C>
__global__ __launch_bounds__(256) void dist_kernel(const float* __restrict__ x,
                                                   float* __restrict__ D) {
  constexpr int CH = (C < 64) ? C : 64;
  constexpr int NP = C / CH;
  constexpr int S = CH + 2;
  __shared__ float xs[NN * S];
  __shared__ float sq[NN];
  int b = blockIdx.x >> 2, qr = blockIdx.x & 3;
  const float* xb = x + (size_t)b * NN * C;
  int rg = threadIdx.x >> 5, cg = threadIdx.x & 31;
  int r0 = qr * 32 + rg * 4;

  float acc[4][4];
#pragma unroll
  for (int i = 0; i < 4; ++i)
#pragma unroll
    for (int j = 0; j < 4; ++j) acc[i][j] = 0.f;
  float sqacc = 0.f;

  for (int ps = 0; ps < NP; ++ps) {
    int c0 = ps * CH;
    __syncthreads();
    for (int t = threadIdx.x; t < NN * CH; t += 256) {
      int row = t / CH, c = t - row * CH;
      xs[row * S + c] = xb[(size_t)row * C + c0 + c];
    }
    __syncthreads();
    if (threadIdx.x < NN) {
      const float* xr = xs + threadIdx.x * S;
      float s = sqacc;
      for (int c = 0; c < CH; ++c) s = fmaf(xr[c], xr[c], s);
      sqacc = s;
    }
    for (int c = 0; c < CH; c += 2) {
      float2 av[4], bv[4];
#pragma unroll
      for (int i = 0; i < 4; ++i) av[i] = *(const float2*)&xs[(r0 + i) * S + c];
#pragma unroll
      for (int j = 0; j < 4; ++j) bv[j] = *(const float2*)&xs[(cg + 32 * j) * S + c];
#pragma unroll
      for (int i = 0; i < 4; ++i)
#pragma unroll
        for (int j = 0; j < 4; ++j) {
          acc[i][j] = fmaf(av[i].x, bv[j].x, acc[i][j]);
          acc[i][j] = fmaf(av[i].y, bv[j].y, acc[i][j]);
        }
    }
  }
  __syncthreads();
  if (threadIdx.x < NN) sq[threadIdx.x] = sqacc;
  __syncthreads();
#pragma unroll
  for (int i = 0; i < 4; ++i) {
    float sn = sq[r0 + i];
#pragma unroll
    for (int j = 0; j < 4; ++j) {
      int m = cg + 32 * j;
      D[((size_t)(b * NN + r0 + i)) * NN + m] = sn - 2.f * acc[i][j] + sq[m];
    }
  }
}

// ---------------------------------------------------------------- kNN: selection
__global__ __launch_bounds__(256) void select_kernel(const float* __restrict__ D,
                                                     int* __restrict__ idx) {
  int lane = threadIdx.x & 63, wv = threadIdx.x >> 6;
  int nd = blockIdx.x * 4 + wv;
  const float* dr = D + (size_t)nd * NN;
  unsigned long long key[2];
  key[0] = (((unsigned long long)ord32(dr[lane])) << 32) | (unsigned)lane;
  key[1] = (((unsigned long long)ord32(dr[lane + 64])) << 32) | (unsigned)(lane + 64);
  int* out = idx + (size_t)nd * KK;
  for (int r = 0; r < KK; ++r) {
    unsigned long long mk = key[0] < key[1] ? key[0] : key[1];
#pragma unroll
    for (int off = 32; off > 0; off >>= 1) {
      unsigned long long o = shfl_xor_u64(mk, off);
      if (o < mk) mk = o;
    }
    int wm = (int)(mk & 0xffffffffu);
    if (lane == 0) out[r] = wm;
    if ((wm & 63) == lane) key[wm >> 6] = ~0ull;
  }
}

// ---------------------------------------------------------------- node GEMM (scalar, layer-1 only)
__global__ __launch_bounds__(256) void node_gemm(const float* __restrict__ x,
                                                 const float* __restrict__ W,
                                                 float* __restrict__ p, float* __restrict__ q,
                                                 int Cin, int Cout) {
  int c = threadIdx.x;
  __shared__ float xr[128];
  for (int r = 0; r < 8; ++r) {
    int row = blockIdx.x * 8 + r;
    __syncthreads();
    for (int i = c; i < Cin; i += blockDim.x) xr[i] = x[(size_t)row * Cin + i];
    __syncthreads();
    float a = 0.f, qv = 0.f;
    for (int i = 0; i < Cin; ++i) {
      float xv = xr[i];
      a  = fmaf(xv, W[i * Cout + c], a);
      qv = fmaf(xv, W[(Cin + i) * Cout + c], qv);
    }
    p[(size_t)row * Cout + c] = a - qv;
    q[(size_t)row * Cout + c] = qv;
  }
}

// ---------------------------------------------------------------- W1 packing (MFMA node GEMM)
// B-matrix [K x N], N=2C: cols [0,C) = W1_top - W1_bot, cols [C,2C) = W1_bot.
// Same 32x32x16 B-fragment layout as pack_w2.
template<int K, int N>
__global__ __launch_bounds__(256) void pack_w1(const float* __restrict__ W1,
                                               u16* __restrict__ Wh, u16* __restrict__ Wl) {
  int t = blockIdx.x * 256 + threadIdx.x;
  if (t >= K * N) return;
  constexpr int C = N / 2;
  constexpr int NT2 = N / 32;
  int j = t & 7, lane = (t >> 3) & 63, tile = t >> 9;
  int nt = tile % NT2, kt = tile / NT2;
  int row = kt * 16 + (lane >> 5) * 8 + j;
  int col = nt * 32 + (lane & 31);
  float w;
  if (col < C) w = W1[row * C + col] - W1[(K + row) * C + col];
  else         w = W1[(K + row) * C + (col - C)];
  u16 h = bf16_rne_bits(w);
  float hf = __uint_as_float(((unsigned)h) << 16);
  Wh[t] = h;
  Wl[t] = bf16_rne_bits(w - hf);
}

// ---------------------------------------------------------------- MFMA node GEMM (layers 2,3)
// Block = 4 waves, one 32-row M-tile; wave wv covers n-tiles [wv*NTQ,(wv+1)*NTQ).
// B staged per k-tile in dbuf LDS; x hi/lo split in regs with prefetch.
template<int K, int N>
__global__ __launch_bounds__(256, 2) void node_gemm_mfma(
    const float* __restrict__ x, const u16* __restrict__ Wh, const u16* __restrict__ Wl,
    float* __restrict__ p, float* __restrict__ q) {
  constexpr int C = N / 2, KT = K / 16, NT2 = N / 32, NTQ = NT2 / 4;
  constexpr int CHK = NT2 * 64;
  __shared__ __align__(16) u16 Bst[2][2][CHK * 8];
  int tid = threadIdx.x, lane = tid & 63, wv = tid >> 6;
  int m = lane & 31, lh = lane >> 5;
  int rowBase = blockIdx.x * 32;
  const float* xr = x + (size_t)(rowBase + m) * K;

  floatx16 acc[NTQ];
#pragma unroll
  for (int nt = 0; nt < NTQ; ++nt)
#pragma unroll
    for (int r = 0; r < 16; ++r) acc[nt][r] = 0.f;

  float4 fxa[2], fxb[2];
  auto loadX = [&](int kt, int buf) {
    int c0 = kt * 16 + lh * 8;
    fxa[buf] = *(const float4*)(xr + c0);
    fxb[buf] = *(const float4*)(xr + c0 + 4);
  };
  auto stage = [&](int kt, int buf) {
    const ushort8_alias* srcH = (const ushort8_alias*)Wh + (size_t)kt * CHK;
    const ushort8_alias* srcL = (const ushort8_alias*)Wl + (size_t)kt * CHK;
    ushort8_alias* dH = (ushort8_alias*)Bst[buf][0];
    ushort8_alias* dL = (ushort8_alias*)Bst[buf][1];
    for (int i = tid; i < CHK; i += 256) { dH[i] = srcH[i]; dL[i] = srcL[i]; }
  };
  loadX(0, 0);
  stage(0, 0);
  __syncthreads();

#pragma unroll 2
  for (int kt = 0; kt < KT; ++kt) {
    int buf = kt & 1;
    if (kt + 1 < KT) { loadX(kt + 1, buf ^ 1); stage(kt + 1, buf ^ 1); }
    float hv[8];
    hv[0] = fxa[buf].x; hv[1] = fxa[buf].y; hv[2] = fxa[buf].z; hv[3] = fxa[buf].w;
    hv[4] = fxb[buf].x; hv[5] = fxb[buf].y; hv[6] = fxb[buf].z; hv[7] = fxb[buf].w;
    bf16x8 ah, al;
#pragma unroll
    for (int t = 0; t < 8; ++t) {
      __bf16 hb = (__bf16)hv[t];
      ah[t] = hb;
      al[t] = (__bf16)(hv[t] - (float)hb);
    }
#pragma unroll
    for (int nt = 0; nt < NTQ; ++nt) {
      int e = (wv * NTQ + nt) * 64 + lane;
      bf16x8 bh = __builtin_bit_cast(bf16x8, ((const ushort8_alias*)Bst[buf][0])[e]);
      bf16x8 bl = __builtin_bit_cast(bf16x8, ((const ushort8_alias*)Bst[buf][1])[e]);
      acc[nt] = __builtin_amdgcn_mfma_f32_32x32x16_bf16(ah, bh, acc[nt], 0, 0, 0);
      acc[nt] = __builtin_amdgcn_mfma_f32_32x32x16_bf16(al, bh, acc[nt], 0, 0, 0);
      acc[nt] = __builtin_amdgcn_mfma_f32_32x32x16_bf16(ah, bl, acc[nt], 0, 0, 0);
    }
    __syncthreads();
  }

#pragma unroll
  for (int nt = 0; nt < NTQ; ++nt) {
    int n = (wv * NTQ + nt) * 32 + m;
    float* dst = (n < C) ? p : q;
    int col = (n < C) ? n : n - C;
#pragma unroll
    for (int r = 0; r < 16; ++r) {
      int row = rowBase + (r & 3) + 8 * (r >> 2) + 4 * lh;
      dst[(size_t)row * C + col] = acc[nt][r];
    }
  }
}

// ---------------------------------------------------------------- BN1 stats (vectorized)
template<int C>
__global__ __launch_bounds__(256) void edge_stats1v(const float* __restrict__ p,
                                                    const float* __restrict__ q,
                                                    const float* __restrict__ b1,
                                                    const int* __restrict__ idx,
                                                    float* __restrict__ s1,
                                                    float* __restrict__ ss1) {
  constexpr int G = C / 4;
  constexpr int KL = 64 / G;
  int tid = threadIdx.x, lane = tid & 63, wv = tid >> 6;
  int nd = blockIdx.x * 4 + wv;
  int b = nd >> 7;
  int g = lane % G, kl = lane / G;

  __shared__ float sS[C], sSS[C];
  if (tid < C) { sS[tid] = 0.f; sSS[tid] = 0.f; }
  __syncthreads();

  const float* pr = p + (size_t)nd * C;
  float4 pv = *(const float4*)(pr + g * 4);
  float4 bv = *(const float4*)(b1 + g * 4);
  pv.x += bv.x; pv.y += bv.y; pv.z += bv.z; pv.w += bv.w;
  float4 s = {0, 0, 0, 0}, ss = {0, 0, 0, 0};
  const int* id = idx + (size_t)nd * KK;
#pragma unroll
  for (int k0 = 0; k0 < KK; k0 += KL) {
    int j = id[k0 + kl];
    float4 q4 = *(const float4*)(q + (size_t)(b * NN + j) * C + g * 4);
    float y;
    y = pv.x + q4.x; s.x += y; ss.x = fmaf(y, y, ss.x);
    y = pv.y + q4.y; s.y += y; ss.y = fmaf(y, y, ss.y);
    y = pv.z + q4.z; s.z += y; ss.z = fmaf(y, y, ss.z);
    y = pv.w + q4.w; s.w += y; ss.w = fmaf(y, y, ss.w);
  }
#pragma unroll
  for (int off = G; off < 64; off <<= 1) {
    s.x += __shfl_xor(s.x, off); ss.x += __shfl_xor(ss.x, off);
    s.y += __shfl_xor(s.y, off); ss.y += __shfl_xor(ss.y, off);
    s.z += __shfl_xor(s.z, off); ss.z += __shfl_xor(ss.z, off);
    s.w += __shfl_xor(s.w, off); ss.w += __shfl_xor(ss.w, off);
  }
  if (kl == 0) {
    atomicAdd(&sS[g * 4 + 0], s.x); atomicAdd(&sSS[g * 4 + 0], ss.x);
    atomicAdd(&sS[g * 4 + 1], s.y); atomicAdd(&sSS[g * 4 + 1], ss.y);
    atomicAdd(&sS[g * 4 + 2], s.z); atomicAdd(&sSS[g * 4 + 2], ss.z);
    atomicAdd(&sS[g * 4 + 3], s.w); atomicAdd(&sSS[g * 4 + 3], ss.w);
  }
  __syncthreads();
  if (tid < C) {
    atomicAdd(&s1[tid], sS[tid]);
    atomicAdd(&ss1[tid], sSS[tid]);
  }
}

// ---------------------------------------------------------------- BN params
__global__ void bn_params(const float* __restrict__ s, const float* __restrict__ ss,
                          const float* __restrict__ g, const float* __restrict__ beta,
                          const float* __restrict__ bias,
                          float M, float* __restrict__ scale, float* __restrict__ shift) {
  int c = threadIdx.x;
  float mean = s[c] / M;
  float var = ss[c] / M - mean * mean;
  if (var < 0.f) var = 0.f;
  float sc = g[c] * rsqrtf(var + 1e-5f);
  scale[c] = sc;
  float sh = beta[c] - mean * sc;
  if (bias) sh += sc * bias[c];
  shift[c] = sh;
}

// ---------------------------------------------------------------- W2 packing (32x32x16)
template<int C>
__global__ __launch_bounds__(256) void pack_w2(const float* __restrict__ W,
                                               u16* __restrict__ Wh, u16* __restrict__ Wl) {
  int t = blockIdx.x * 256 + threadIdx.x;
  if (t >= C * C) return;
  constexpr int NT = C / 32;
  int j = t & 7, lane = (t >> 3) & 63, ktnt = t >> 9;
  int nt = ktnt % NT, kt = ktnt / NT;
  int row = kt * 16 + (lane >> 5) * 8 + j;
  int col = nt * 32 + (lane & 31);
  float w = W[row * C + col];
  u16 h = bf16_rne_bits(w);
  float hf = __uint_as_float(((unsigned)h) << 16);
  Wh[t] = h;
  Wl[t] = bf16_rne_bits(w - hf);
}

// ---------------------------------------------------------------- MFMA edge GEMM2 v4
// v3 + software pipelining: p/q gather loads register-double-buffered (issued one
// k-tile ahead), sc1/sh1 preloaded into LDS. B dbuf in LDS as before.
template<int C>
__global__ __launch_bounds__(256, 2) void edge_gemm2_v4(
    const float* __restrict__ p, const float* __restrict__ q,
    const int* __restrict__ idx,
    const float* __restrict__ sc1, const float* __restrict__ sh1,  // bias1 folded into sh1
    const u16* __restrict__ Wh, const u16* __restrict__ Wl,
    const float* __restrict__ b2,
    float* __restrict__ zmax, float* __restrict__ zmin,
    float* __restrict__ s2, float* __restrict__ ss2) {
  constexpr int KT = C / 16, NT = C / 32, NTH = NT / 2;
  constexpr int CHK = NT * 64;
  __shared__ __align__(16) u16 Bst[2][2][CHK * 8];
  __shared__ float sS[C], sSS[C], sScl[C], sShf[C];
  int tid = threadIdx.x, lane = tid & 63, wv = tid >> 6;
  int m = lane & 31, lh = lane >> 5;
  int mpair = wv >> 1, nhalf = wv & 1;

  if (tid < C) {
    sS[tid] = 0.f; sSS[tid] = 0.f;
    sScl[tid] = sc1[tid]; sShf[tid] = sh1[tid];
  }

  // XCD swizzle: 2048 blocks, 8 nodes/block, 16 blocks/batch share an XCD.
  int u = blockIdx.x >> 3, xcd = blockIdx.x & 7;
  int b = xcd + 8 * (u >> 4);
  int nodeBase = b * NN + (u & 15) * 8;
  int wBase = nodeBase + mpair * 4;

  const float *pr[2], *qr[2];
#pragma unroll
  for (int mt = 0; mt < 2; ++mt) {
    int nd = wBase + mt * 2 + (m >> 4);
    int j = idx[(size_t)nd * KK + (m & 15)];
    pr[mt] = p + (size_t)nd * C;
    qr[mt] = q + (size_t)(b * NN + j) * C;
  }

  floatx16 acc[2][NTH];
#pragma unroll
  for (int mt = 0; mt < 2; ++mt)
#pragma unroll
    for (int nt = 0; nt < NTH; ++nt) {
      float bv = b2[(nhalf * NTH + nt) * 32 + m];
#pragma unroll
      for (int r = 0; r < 16; ++r) acc[mt][nt][r] = bv;
    }

  float4 fpa[2][2], fpb[2][2], fqa[2][2], fqb[2][2];  // [buf][mt]
  auto loadPQ = [&](int kt, int buf) {
    int c0 = kt * 16 + lh * 8;
#pragma unroll
    for (int mt = 0; mt < 2; ++mt) {
      fpa[buf][mt] = *(const float4*)(pr[mt] + c0);
      fpb[buf][mt] = *(const float4*)(pr[mt] + c0 + 4);
      fqa[buf][mt] = *(const float4*)(qr[mt] + c0);
      fqb[buf][mt] = *(const float4*)(qr[mt] + c0 + 4);
    }
  };
  auto stage = [&](int kt, int buf) {
    const ushort8_alias* srcH = (const ushort8_alias*)Wh + (size_t)kt * CHK;
    const ushort8_alias* srcL = (const ushort8_alias*)Wl + (size_t)kt * CHK;
    ushort8_alias* dH = (ushort8_alias*)Bst[buf][0];
    ushort8_alias* dL = (ushort8_alias*)Bst[buf][1];
    for (int i = tid; i < CHK; i += 256) { dH[i] = srcH[i]; dL[i] = srcL[i]; }
  };
  loadPQ(0, 0);
  stage(0, 0);
  __syncthreads();

#pragma unroll 2
  for (int kt = 0; kt < KT; ++kt) {
    int buf = kt & 1;
    if (kt + 1 < KT) { loadPQ(kt + 1, buf ^ 1); stage(kt + 1, buf ^ 1); }

    int c0 = kt * 16 + lh * 8;
    float4 sa = *(const float4*)(sScl + c0);
    float4 sb = *(const float4*)(sScl + c0 + 4);
    float4 ta = *(const float4*)(sShf + c0);
    float4 tb = *(const float4*)(sShf + c0 + 4);
    bf16x8 ah[2], al[2];
#pragma unroll
    for (int mt = 0; mt < 2; ++mt) {
      float hv[8];
      hv[0] = fmaxf(fmaf(fpa[buf][mt].x + fqa[buf][mt].x, sa.x, ta.x), 0.f);
      hv[1] = fmaxf(fmaf(fpa[buf][mt].y + fqa[buf][mt].y, sa.y, ta.y), 0.f);
      hv[2] = fmaxf(fmaf(fpa[buf][mt].z + fqa[buf][mt].z, sa.z, ta.z), 0.f);
      hv[3] = fmaxf(fmaf(fpa[buf][mt].w + fqa[buf][mt].w, sa.w, ta.w), 0.f);
      hv[4] = fmaxf(fmaf(fpb[buf][mt].x + fqb[buf][mt].x, sb.x, tb.x), 0.f);
      hv[5] = fmaxf(fmaf(fpb[buf][mt].y + fqb[buf][mt].y, sb.y, tb.y), 0.f);
      hv[6] = fmaxf(fmaf(fpb[buf][mt].z + fqb[buf][mt].z, sb.z, tb.z), 0.f);
      hv[7] = fmaxf(fmaf(fpb[buf][mt].w + fqb[buf][mt].w, sb.w, tb.w), 0.f);
#pragma unroll
      for (int t = 0; t < 8; ++t) {
        __bf16 hb = (__bf16)hv[t];
        ah[mt][t] = hb;
        al[mt][t] = (__bf16)(hv[t] - (float)hb);
      }
    }

#pragma unroll
    for (int nt = 0; nt < NTH; ++nt) {
      int e = (nhalf * NTH + nt) * 64 + lane;
      bf16x8 bh = __builtin_bit_cast(bf16x8, ((const ushort8_alias*)Bst[buf][0])[e]);
      bf16x8 bl = __builtin_bit_cast(bf16x8, ((const ushort8_alias*)Bst[buf][1])[e]);
#pragma unroll
      for (int mt = 0; mt < 2; ++mt) {
        acc[mt][nt] = __builtin_amdgcn_mfma_f32_32x32x16_bf16(ah[mt], bh, acc[mt][nt], 0, 0, 0);
        acc[mt][nt] = __builtin_amdgcn_mfma_f32_32x32x16_bf16(al[mt], bh, acc[mt][nt], 0, 0, 0);
        acc[mt][nt] = __builtin_amdgcn_mfma_f32_32x32x16_bf16(ah[mt], bl, acc[mt][nt], 0, 0, 0);
      }
    }
    __syncthreads();
  }

  // epilogue: acc row = (r&3)+8*(r>>2)+4*lh; regs 0..7 -> first node, 8..15 -> second.
#pragma unroll
  for (int mt = 0; mt < 2; ++mt)
#pragma unroll
    for (int nt = 0; nt < NTH; ++nt) {
      float s = 0.f, ss = 0.f;
      float mxA = -INFINITY, mnA = INFINITY, mxB = -INFINITY, mnB = INFINITY;
#pragma unroll
      for (int r = 0; r < 8; ++r) {
        float z = acc[mt][nt][r];
        s += z; ss = fmaf(z, z, ss);
        mxA = fmaxf(mxA, z); mnA = fminf(mnA, z);
      }
#pragma unroll
      for (int r = 8; r < 16; ++r) {
        float z = acc[mt][nt][r];
        s += z; ss = fmaf(z, z, ss);
        mxB = fmaxf(mxB, z); mnB = fminf(mnB, z);
      }
      mxA = fmaxf(mxA, __shfl_xor(mxA, 32)); mnA = fminf(mnA, __shfl_xor(mnA, 32));
      mxB = fmaxf(mxB, __shfl_xor(mxB, 32)); mnB = fminf(mnB, __shfl_xor(mnB, 32));
      float sw = s + __shfl_xor(s, 32);
      float ssw = ss + __shfl_xor(ss, 32);
      if (lane < 32) {
        int col = (nhalf * NTH + nt) * 32 + m;
        int ndA = wBase + mt * 2;
        zmax[(size_t)ndA * C + col] = mxA;
        zmin[(size_t)ndA * C + col] = mnA;
        zmax[(size_t)(ndA + 1) * C + col] = mxB;
        zmin[(size_t)(ndA + 1) * C + col] = mnB;
        atomicAdd(&sS[col], sw);
        atomicAdd(&sSS[col], ssw);
      }
    }
  __syncthreads();
  if (tid < C) {
    atomicAdd(&s2[tid], sS[tid]);
    atomicAdd(&ss2[tid], sSS[tid]);
  }
}

// ---------------------------------------------------------------- finalize
__global__ __launch_bounds__(256) void finalize_kernel(const float* __restrict__ zmax,
                                                       const float* __restrict__ zmin,
                                                       const float* __restrict__ sc2,
                                                       const float* __restrict__ sh2,
                                                       float* __restrict__ out, int Cmask) {
  int t = blockIdx.x * 256 + threadIdx.x;
  int c = t & Cmask;
  float scl = sc2[c];
  float v = (scl >= 0.f) ? zmax[t] : zmin[t];
  out[t] = fmaxf(fmaf(v, scl, sh2[c]), 0.f);
}

// ---------------------------------------------------------------- pooling
__global__ __launch_bounds__(256) void pool_kernel(const float* __restrict__ h,
                                                   float* __restrict__ pooled) {
  int b = blockIdx.x, c = threadIdx.x;
  float s = 0.f, mx = -INFINITY;
  for (int n = 0; n < NN; ++n) {
    float v = h[(size_t)(b * NN + n) * 256 + c];
    s += v;
    mx = fmaxf(mx, v);
  }
  pooled[b * 512 + c] = s * (1.f / 128.f);
  pooled[b * 512 + 256 + c] = mx;
}

// ---------------------------------------------------------------- FC tail
__global__ __launch_bounds__(256) void fc1_fused(const float* __restrict__ pooled,
                                                 const float* __restrict__ W,
                                                 const float* __restrict__ bias,
                                                 float* __restrict__ t1raw,
                                                 float* __restrict__ fs, float* __restrict__ fss) {
  int b = blockIdx.x, c = threadIdx.x;
  __shared__ float row[512];
  row[c] = pooled[b * 512 + c];
  row[c + 256] = pooled[b * 512 + 256 + c];
  __syncthreads();
  float acc = bias[c];
  for (int i = 0; i < 512; ++i) acc = fmaf(row[i], W[i * 256 + c], acc);
  t1raw[b * 256 + c] = acc;
  atomicAdd(&fs[c], acc);
  atomicAdd(&fss[c], acc * acc);
}

__global__ __launch_bounds__(256) void fc2_fused(const float* __restrict__ t1raw,
                                                 const float* __restrict__ sc,
                                                 const float* __restrict__ sh,
                                                 const float* __restrict__ W,
                                                 const float* __restrict__ bias,
                                                 float* __restrict__ t2raw,
                                                 float* __restrict__ gs, float* __restrict__ gss) {
  int b = blockIdx.x, c = threadIdx.x;
  __shared__ float row[256];
  row[c] = fmaxf(fmaf(t1raw[b * 256 + c], sc[c], sh[c]), 0.f);
  __syncthreads();
  if (c < 128) {
    float acc = bias[c];
    for (int i = 0; i < 256; ++i) acc = fmaf(row[i], W[i * 128 + c], acc);
    t2raw[b * 128 + c] = acc;
    atomicAdd(&gs[c], acc);
    atomicAdd(&gss[c], acc * acc);
  }
}

__global__ __launch_bounds__(256) void fc3_fused(const float* __restrict__ t2raw,
                                                 const float* __restrict__ sc,
                                                 const float* __restrict__ sh,
                                                 const float* __restrict__ W,
                                                 const float* __restrict__ bias,
                                                 float* __restrict__ out) {
  int t = threadIdx.x;
  int b = t >> 1, jj = t & 1;
  float acc = bias[jj];
  for (int r = 0; r < 128; ++r) {
    float v = fmaxf(fmaf(t2raw[b * 128 + r], sc[r], sh[r]), 0.f);
    acc = fmaf(v, W[r * 2 + jj], acc);
  }
  out[t] = acc;
}

// ---------------------------------------------------------------- per-layer driver

struct LayerPtrs {
  int* idx; float *p, *q, *zmx, *zmn, *stats, *D;
  u16 *Wh, *Wl, *Wh1, *Wl1;
};

template<int Cin, int C>
static void run_edgeconv(const float* xin,
                         const float* W1, const float* b1, const float* g1, const float* e1,
                         const float* W2, const float* b2, const float* g2, const float* e2,
                         float* hout, const LayerPtrs& L, hipStream_t stream) {
  float* s1 = L.stats;
  float* ss1 = L.stats + 256;
  float* s2 = L.stats + 512;
  float* ss2 = L.stats + 768;
  float* sc1 = L.stats + 1024;
  float* sh1 = L.stats + 1280;
  float* sc2 = L.stats + 1536;
  float* sh2 = L.stats + 1792;

  (void)hipMemsetAsync(L.stats, 0, 4 * 256 * sizeof(float), stream);
  dist_kernel<Cin><<<dim3(BB * 4), dim3(256), 0, stream>>>(xin, L.D);
  select_kernel<<<dim3(MNODE / 4), dim3(256), 0, stream>>>(L.D, L.idx);
  if constexpr (Cin >= 16) {
    pack_w1<Cin, 2 * C><<<dim3((Cin * 2 * C + 255) / 256), dim3(256), 0, stream>>>(W1, L.Wh1, L.Wl1);
    node_gemm_mfma<Cin, 2 * C><<<dim3(MNODE / 32), dim3(256), 0, stream>>>(xin, L.Wh1, L.Wl1, L.p, L.q);
  } else {
    node_gemm<<<dim3(MNODE / 8), dim3(C), 0, stream>>>(xin, W1, L.p, L.q, Cin, C);
  }
  pack_w2<C><<<dim3((C * C + 255) / 256), dim3(256), 0, stream>>>(W2, L.Wh, L.Wl);
  edge_stats1v<C><<<dim3(MNODE / 4), dim3(256), 0, stream>>>(L.p, L.q, b1, L.idx, s1, ss1);
  bn_params<<<dim3(1), dim3(C), 0, stream>>>(s1, ss1, g1, e1, b1, (float)MEDGE, sc1, sh1);
  edge_gemm2_v4<C><<<dim3(MNODE / 8), dim3(256), 0, stream>>>(
      L.p, L.q, L.idx, sc1, sh1, L.Wh, L.Wl, b2, L.zmx, L.zmn, s2, ss2);
  bn_params<<<dim3(1), dim3(C), 0, stream>>>(s2, ss2, g2, e2, nullptr, (float)MEDGE, sc2, sh2);
  finalize_kernel<<<dim3(MNODE * C / 256), dim3(256), 0, stream>>>(L.zmx, L.zmn, sc2, sh2,
                                                                   hout, C - 1);
}

// ---------------------------------------------------------------- launch

extern "C" void kernel_launch(void* const* d_in, const int* in_sizes, int n_in,
                              void* d_out, int out_size, void* d_ws, size_t ws_size,
                              hipStream_t stream) {
  const float* x   = (const float*)d_in[0];
  const float* w11 = (const float*)d_in[1];
  const float* b11 = (const float*)d_in[2];
  const float* g11 = (const float*)d_in[3];
  const float* e11 = (const float*)d_in[4];
  const float* w12 = (const float*)d_in[5];
  const float* b12 = (const float*)d_in[6];
  const float* g12 = (const float*)d_in[7];
  const float* e12 = (const float*)d_in[8];
  const float* w21 = (const float*)d_in[9];
  const float* b21 = (const float*)d_in[10];
  const float* g21 = (const float*)d_in[11];
  const float* e21 = (const float*)d_in[12];
  const float* w22 = (const float*)d_in[13];
  const float* b22 = (const float*)d_in[14];
  const float* g22 = (const float*)d_in[15];
  const float* e22 = (const float*)d_in[16];
  const float* w31 = (const float*)d_in[17];
  const float* b31 = (const float*)d_in[18];
  const float* g31 = (const float*)d_in[19];
  const float* e31 = (const float*)d_in[20];
  const float* w32 = (const float*)d_in[21];
  const float* b32 = (const float*)d_in[22];
  const float* g32 = (const float*)d_in[23];
  const float* e32 = (const float*)d_in[24];
  const float* fw1 = (const float*)d_in[25];
  const float* fb1 = (const float*)d_in[26];
  const float* fg1 = (const float*)d_in[27];
  const float* fe1 = (const float*)d_in[28];
  const float* fw2 = (const float*)d_in[29];
  const float* fb2 = (const float*)d_in[30];
  const float* fg2 = (const float*)d_in[31];
  const float* fe2 = (const float*)d_in[32];
  const float* fw3 = (const float*)d_in[33];
  const float* fb3 = (const float*)d_in[34];

  char* wsb = (char*)d_ws;
  size_t o = 0;
  auto alloc = [&](size_t bytes) -> void* {
    void* r = wsb + o;
    o += (bytes + 255) & ~(size_t)255;
    return r;
  };
  LayerPtrs L;
  L.idx   = (int*)  alloc((size_t)MNODE * KK * sizeof(int));
  L.p     = (float*)alloc((size_t)MNODE * 256 * sizeof(float));
  L.q     = (float*)alloc((size_t)MNODE * 256 * sizeof(float));
  L.zmx   = (float*)alloc((size_t)MNODE * 256 * sizeof(float));
  L.zmn   = (float*)alloc((size_t)MNODE * 256 * sizeof(float));
  L.stats = (float*)alloc(8 * 256 * sizeof(float));
  L.D     = (float*)alloc((size_t)MNODE * NN * sizeof(float));
  L.Wh    = (u16*)  alloc((size_t)256 * 256 * sizeof(u16));
  L.Wl    = (u16*)  alloc((size_t)256 * 256 * sizeof(u16));
  L.Wh1   = (u16*)  alloc((size_t)128 * 512 * sizeof(u16));
  L.Wl1   = (u16*)  alloc((size_t)128 * 512 * sizeof(u16));
  float* h1buf   = (float*)alloc((size_t)MNODE * 64 * sizeof(float));
  float* h2buf   = (float*)alloc((size_t)MNODE * 128 * sizeof(float));
  float* h3buf   = (float*)alloc((size_t)MNODE * 256 * sizeof(float));
  float* pooled  = (float*)alloc(128 * 512 * sizeof(float));
  float* t1raw   = (float*)alloc(128 * 256 * sizeof(float));
  float* t2raw   = (float*)alloc(128 * 128 * sizeof(float));
  float* fcstats = (float*)alloc(8 * 256 * sizeof(float));

  float* fs  = fcstats;
  float* fss = fcstats + 256;
  float* fsc = fcstats + 512;
  float* fsh = fcstats + 768;
  float* gs  = fcstats + 1024;
  float* gss = fcstats + 1280;
  float* gsc = fcstats + 1536;
  float* gsh = fcstats + 1792;

  (void)hipMemsetAsync(fcstats, 0, 8 * 256 * sizeof(float), stream);

  run_edgeconv<6,   64 >(x,     w11, b11, g11, e11, w12, b12, g12, e12, h1buf, L, stream);
  run_edgeconv<64,  128>(h1buf, w21, b21, g21, e21, w22, b22, g22, e22, h2buf, L, stream);
  run_edgeconv<128, 256>(h2buf, w31, b31, g31, e31, w32, b32, g32, e32, h3buf, L, stream);

  pool_kernel<<<dim3(BB), dim3(256), 0, stream>>>(h3buf, pooled);
  fc1_fused<<<dim3(BB), dim3(256), 0, stream>>>(pooled, fw1, fb1, t1raw, fs, fss);
  bn_params<<<dim3(1), dim3(256), 0, stream>>>(fs, fss, fg1, fe1, nullptr, 128.f, fsc, fsh);
  fc2_fused<<<dim3(BB), dim3(256), 0, stream>>>(t1raw, fsc, fsh, fw2, fb2, t2raw, gs, gss);
  bn_params<<<dim3(1), dim3(128), 0, stream>>>(gs, gss, fg2, fe2, nullptr, 128.f, gsc, gsh);
  fc3_fused<<<dim3(1), dim3(256), 0, stream>>>(t2raw, gsc, gsh, fw3, fb3, (float*)d_out);
}